// Round 1
// baseline (1592.459 us; speedup 1.0000x reference)
//
#include <hip/hip_runtime.h>
#include <math.h>

#define TT 1024
#define BB 4
#define HH 1024
#define NHH 32
#define DD 32
#define MMX 2
#define ROWS (BB*TT)

__device__ __forceinline__ float sigmoidf_(float x){ return 1.f/(1.f+expf(-x)); }

// ---------------- RoPE cos/sin table: ct/st[t*16+j] ----------------
__global__ __launch_bounds__(256) void rope_table_k(float* __restrict__ ct, float* __restrict__ st){
  int idx = blockIdx.x*256 + threadIdx.x;   // 16384 = 1024*16
  int t = idx >> 4, j = idx & 15;
  float invf = powf(10000.f, -(float)j/16.f);
  float ang = (float)t * invf;
  ct[idx] = cosf(ang);
  st[idx] = sinf(ang);
}

// ---------------- generic fp32 GEMM: C[4096,N] = A[4096,K] @ W[N,K]^T (+bias)(+res) ----
__global__ __launch_bounds__(256) void gemm_bt_k(
    const float* __restrict__ A, const float* __restrict__ W,
    const float* __restrict__ bias, const float* __restrict__ res,
    float* __restrict__ C, int N, int K)
{
  __shared__ float As[16][68];
  __shared__ float Bs[16][68];
  const int tid = threadIdx.x;
  const int row0 = blockIdx.y * 64, col0 = blockIdx.x * 64;
  const int lr = tid >> 2, lq = tid & 3;   // load: row, k-quad
  const int tr = tid >> 4, tc = tid & 15;  // compute: 4x4 microtile
  float acc[4][4] = {};
  for (int k0 = 0; k0 < K; k0 += 16) {
    float4 av = *reinterpret_cast<const float4*>(A + (size_t)(row0+lr)*K + k0 + lq*4);
    float4 bv = *reinterpret_cast<const float4*>(W + (size_t)(col0+lr)*K + k0 + lq*4);
    __syncthreads();
    As[lq*4+0][lr]=av.x; As[lq*4+1][lr]=av.y; As[lq*4+2][lr]=av.z; As[lq*4+3][lr]=av.w;
    Bs[lq*4+0][lr]=bv.x; Bs[lq*4+1][lr]=bv.y; Bs[lq*4+2][lr]=bv.z; Bs[lq*4+3][lr]=bv.w;
    __syncthreads();
    #pragma unroll
    for (int kk = 0; kk < 16; kk++) {
      float4 a4 = *reinterpret_cast<const float4*>(&As[kk][tr*4]);
      float4 b4 = *reinterpret_cast<const float4*>(&Bs[kk][tc*4]);
      float aa[4] = {a4.x,a4.y,a4.z,a4.w};
      float bb[4] = {b4.x,b4.y,b4.z,b4.w};
      #pragma unroll
      for (int ii=0; ii<4; ii++)
        #pragma unroll
        for (int jj=0; jj<4; jj++)
          acc[ii][jj] = fmaf(aa[ii], bb[jj], acc[ii][jj]);
    }
  }
  #pragma unroll
  for (int ii=0; ii<4; ii++){
    int r = row0 + tr*4 + ii;
    #pragma unroll
    for (int jj=0; jj<4; jj++){
      int c = col0 + tc*4 + jj;
      float v = acc[ii][jj];
      if (bias) v += bias[c];
      if (res)  v += res[(size_t)r*N + c];
      C[(size_t)r*N + c] = v;
    }
  }
}

// ---------------- RoPE + (elu+1), in place on qraw/kraw ----------------
__global__ __launch_bounds__(256) void rope_phi_k(
    float* __restrict__ q, float* __restrict__ k,
    const float* __restrict__ ct, const float* __restrict__ st)
{
  int idx = blockIdx.x*256 + threadIdx.x;   // ROWS*32*16 = 2097152
  int i = idx >> 9;
  int h = (idx >> 4) & 31;
  int j = idx & 15;
  int t = i & (TT-1);
  float c = ct[t*16+j], s = st[t*16+j];
  size_t base = (size_t)i*HH + h*32;
  float q1 = q[base+j], q2 = q[base+16+j];
  float k1 = k[base+j], k2 = k[base+16+j];
  float r1 = q1*c - q2*s, r2 = q1*s + q2*c;
  q[base+j]    = r1 > 0.f ? r1+1.f : expf(r1);
  q[base+16+j] = r2 > 0.f ? r2+1.f : expf(r2);
  r1 = k1*c - k2*s; r2 = k1*s + k2*c;
  k[base+j]    = r1 > 0.f ? r1+1.f : expf(r1);
  k[base+16+j] = r2 > 0.f ? r2+1.f : expf(r2);
}

// ---------------- beta = clip(sigmoid), mix = softmax over M=2 ----------------
__global__ __launch_bounds__(256) void beta_mix_k(
    const float* __restrict__ braw, const float* __restrict__ mraw,
    float* __restrict__ beta, float* __restrict__ mix)
{
  int idx = blockIdx.x*256 + threadIdx.x;   // ROWS*32 = 131072
  int off = idx*2;
  float b0 = sigmoidf_(braw[off]), b1 = sigmoidf_(braw[off+1]);
  beta[off]   = fminf(fmaxf(b0, 0.85f), 0.9995f);
  beta[off+1] = fminf(fmaxf(b1, 0.85f), 0.9995f);
  float a0 = mraw[off], a1 = mraw[off+1];
  float mxv = fmaxf(a0,a1);
  float e0 = expf(a0-mxv), e1 = expf(a1-mxv);
  float inv = 1.f/(e0+e1);
  mix[off] = e0*inv; mix[off+1] = e1*inv;
}

// ---------------- sequential scan: one wave per (b,h); lane = m*32+c ----------------
__global__ __launch_bounds__(64) void scan_k(
    const float* __restrict__ phi_q, const float* __restrict__ phi_k,
    const float* __restrict__ v, const float* __restrict__ beta,
    const float* __restrict__ mix, float* __restrict__ y)
{
  const int bid = blockIdx.x;      // 0..127 : b*32 + h
  const int b = bid >> 5, h = bid & 31;
  const int lane = threadIdx.x;
  const int c = lane & 31;
  const int m = lane >> 5;
  float S[32];
  #pragma unroll
  for (int d=0; d<32; d++) S[d]=0.f;
  float Kc = 0.f;
  for (int t=0; t<TT; t++) {
    const int i = b*TT + t;
    const size_t base = (size_t)i*HH + h*32;
    const float4* q4 = reinterpret_cast<const float4*>(phi_q + base);
    const float4* k4 = reinterpret_cast<const float4*>(phi_k + base);
    float tq[32], tk[32];
    #pragma unroll
    for (int u=0; u<8; u++){
      float4 aq = q4[u]; tq[4*u]=aq.x; tq[4*u+1]=aq.y; tq[4*u+2]=aq.z; tq[4*u+3]=aq.w;
      float4 ak = k4[u]; tk[4*u]=ak.x; tk[4*u+1]=ak.y; tk[4*u+2]=ak.z; tk[4*u+3]=ak.w;
    }
    const float vc  = v[base + c];
    const float pqc = phi_q[base + c];
    const float pkc = phi_k[base + c];
    const int bm = (i*NHH + h)*MMX + m;
    const float bet = beta[bm];
    const float mxw = mix[bm];
    // K update + den = phi_q . K (reduce within each 32-lane half = per-m)
    Kc = fmaf(Kc, bet, pkc);
    float den = pqc * Kc;
    den += __shfl_xor(den, 1);
    den += __shfl_xor(den, 2);
    den += __shfl_xor(den, 4);
    den += __shfl_xor(den, 8);
    den += __shfl_xor(den, 16);
    den += 1e-6f;
    // S update + num = phi_q . S[:,c]
    float num = 0.f;
    #pragma unroll
    for (int d=0; d<32; d++){
      S[d] = fmaf(S[d], bet, tk[d]*vc);
      num = fmaf(tq[d], S[d], num);
    }
    float w = num / den * mxw;
    w += __shfl_xor(w, 32);   // sum the two m contributions
    if (lane < 32) y[(size_t)i*HH + h*32 + c] = w;
  }
}

// ---------------- LayerNorm over rows of 1024 ----------------
__global__ __launch_bounds__(256) void ln_k(
    const float* __restrict__ z, const float* __restrict__ g,
    const float* __restrict__ bta, float* __restrict__ out)
{
  const int row = blockIdx.x;
  const int tid = threadIdx.x;
  const float* zr = z + (size_t)row*HH;
  float4 zv = reinterpret_cast<const float4*>(zr)[tid];
  float sum = zv.x+zv.y+zv.z+zv.w;
  float sq  = zv.x*zv.x + zv.y*zv.y + zv.z*zv.z + zv.w*zv.w;
  #pragma unroll
  for (int off=1; off<64; off<<=1){ sum += __shfl_xor(sum, off); sq += __shfl_xor(sq, off); }
  __shared__ float s1[4], s2[4];
  int w = tid>>6;
  if ((tid&63)==0){ s1[w]=sum; s2[w]=sq; }
  __syncthreads();
  sum = s1[0]+s1[1]+s1[2]+s1[3];
  sq  = s2[0]+s2[1]+s2[2]+s2[3];
  float mu  = sum * (1.f/1024.f);
  float var = sq * (1.f/1024.f) - mu*mu;
  float rstd = rsqrtf(var + 1e-5f);
  float4 gv = reinterpret_cast<const float4*>(g)[tid];
  float4 bv = reinterpret_cast<const float4*>(bta)[tid];
  float4 ov;
  ov.x = (zv.x-mu)*rstd*gv.x + bv.x;
  ov.y = (zv.y-mu)*rstd*gv.y + bv.y;
  ov.z = (zv.z-mu)*rstd*gv.z + bv.z;
  ov.w = (zv.w-mu)*rstd*gv.w + bv.w;
  reinterpret_cast<float4*>(out + (size_t)row*HH)[tid] = ov;
}

extern "C" void kernel_launch(void* const* d_in, const int* in_sizes, int n_in,
                              void* d_out, int out_size, void* d_ws, size_t ws_size,
                              hipStream_t stream)
{
  const float* x     = (const float*)d_in[0];
  const float* Wq    = (const float*)d_in[1];
  const float* Wk    = (const float*)d_in[2];
  const float* Wv    = (const float*)d_in[3];
  const float* Wbeta = (const float*)d_in[4];
  const float* bbeta = (const float*)d_in[5];
  const float* Wmix  = (const float*)d_in[6];
  const float* bmix  = (const float*)d_in[7];
  const float* Wout  = (const float*)d_in[8];
  const float* bout  = (const float*)d_in[9];
  const float* ln_g  = (const float*)d_in[10];
  const float* ln_b  = (const float*)d_in[11];
  float* out = (float*)d_out;

  float* ws = (float*)d_ws;
  float* ct   = ws;                  // 16384
  float* st   = ct + 16384;          // 16384
  float* qraw = st + 16384;          // 4194304  (becomes phi_q in place)
  float* kraw = qraw + 4194304;      // 4194304  (becomes phi_k in place)
  float* vraw = kraw + 4194304;      // 4194304  (reused as z after scan)
  float* braw = vraw + 4194304;      // 262144
  float* mraw = braw + 262144;       // 262144
  float* beta = mraw + 262144;       // 262144
  float* mix  = beta + 262144;       // 262144
  float* y    = mix  + 262144;       // 4194304
  float* z    = vraw;

  rope_table_k<<<64, 256, 0, stream>>>(ct, st);
  dim3 g16(16, 64), g1(1, 64);
  gemm_bt_k<<<g16, 256, 0, stream>>>(x, Wq,    nullptr, nullptr, qraw, 1024, 1024);
  gemm_bt_k<<<g16, 256, 0, stream>>>(x, Wk,    nullptr, nullptr, kraw, 1024, 1024);
  gemm_bt_k<<<g16, 256, 0, stream>>>(x, Wv,    nullptr, nullptr, vraw, 1024, 1024);
  gemm_bt_k<<<g1,  256, 0, stream>>>(x, Wbeta, bbeta,   nullptr, braw,   64, 1024);
  gemm_bt_k<<<g1,  256, 0, stream>>>(x, Wmix,  bmix,    nullptr, mraw,   64, 1024);
  rope_phi_k<<<8192, 256, 0, stream>>>(qraw, kraw, ct, st);
  beta_mix_k<<<512, 256, 0, stream>>>(braw, mraw, beta, mix);
  scan_k<<<128, 64, 0, stream>>>(qraw, kraw, vraw, beta, mix, y);
  gemm_bt_k<<<g16, 256, 0, stream>>>(y, Wout, bout, x, z, 1024, 1024);
  ln_k<<<4096, 256, 0, stream>>>(z, ln_g, ln_b, out);
}

// Round 2
// 1173.775 us; speedup vs baseline: 1.3567x; 1.3567x over previous
//
#include <hip/hip_runtime.h>
#include <math.h>

#define TT 1024
#define BB 4
#define HH 1024
#define NHH 32
#define CL 64
#define NCH (TT/CL)

__device__ __forceinline__ float sigmoidf_(float x){ return 1.f/(1.f+expf(-x)); }

// ---------------- RoPE cos/sin table: ct/st[t*16+j] ----------------
__global__ __launch_bounds__(256) void rope_table_k(float* __restrict__ ct, float* __restrict__ st){
  int idx = blockIdx.x*256 + threadIdx.x;   // 16384 = 1024*16
  int t = idx >> 4, j = idx & 15;
  float invf = powf(10000.f, -(float)j/16.f);
  float ang = (float)t * invf;
  ct[idx] = cosf(ang);
  st[idx] = sinf(ang);
}

// ---------------- generic fp32 GEMM: C[4096,N] = A[4096,K] @ W[N,K]^T (+bias)(+res) ----
__global__ __launch_bounds__(256) void gemm_bt_k(
    const float* __restrict__ A, const float* __restrict__ W,
    const float* __restrict__ bias, const float* __restrict__ res,
    float* __restrict__ C, int N, int K)
{
  __shared__ float As[16][68];
  __shared__ float Bs[16][68];
  const int tid = threadIdx.x;
  const int row0 = blockIdx.y * 64, col0 = blockIdx.x * 64;
  const int lr = tid >> 2, lq = tid & 3;
  const int tr = tid >> 4, tc = tid & 15;
  float acc[4][4] = {};
  for (int k0 = 0; k0 < K; k0 += 16) {
    float4 av = *reinterpret_cast<const float4*>(A + (size_t)(row0+lr)*K + k0 + lq*4);
    float4 bv = *reinterpret_cast<const float4*>(W + (size_t)(col0+lr)*K + k0 + lq*4);
    __syncthreads();
    As[lq*4+0][lr]=av.x; As[lq*4+1][lr]=av.y; As[lq*4+2][lr]=av.z; As[lq*4+3][lr]=av.w;
    Bs[lq*4+0][lr]=bv.x; Bs[lq*4+1][lr]=bv.y; Bs[lq*4+2][lr]=bv.z; Bs[lq*4+3][lr]=bv.w;
    __syncthreads();
    #pragma unroll
    for (int kk = 0; kk < 16; kk++) {
      float4 a4 = *reinterpret_cast<const float4*>(&As[kk][tr*4]);
      float4 b4 = *reinterpret_cast<const float4*>(&Bs[kk][tc*4]);
      float aa[4] = {a4.x,a4.y,a4.z,a4.w};
      float bb[4] = {b4.x,b4.y,b4.z,b4.w};
      #pragma unroll
      for (int ii=0; ii<4; ii++)
        #pragma unroll
        for (int jj=0; jj<4; jj++)
          acc[ii][jj] = fmaf(aa[ii], bb[jj], acc[ii][jj]);
    }
  }
  #pragma unroll
  for (int ii=0; ii<4; ii++){
    int r = row0 + tr*4 + ii;
    #pragma unroll
    for (int jj=0; jj<4; jj++){
      int c = col0 + tc*4 + jj;
      float v = acc[ii][jj];
      if (bias) v += bias[c];
      if (res)  v += res[(size_t)r*N + c];
      C[(size_t)r*N + c] = v;
    }
  }
}

// ---------------- RoPE + (elu+1), in place on qraw/kraw ----------------
__global__ __launch_bounds__(256) void rope_phi_k(
    float* __restrict__ q, float* __restrict__ k,
    const float* __restrict__ ct, const float* __restrict__ st)
{
  int idx = blockIdx.x*256 + threadIdx.x;
  int i = idx >> 9;
  int h = (idx >> 4) & 31;
  int j = idx & 15;
  int t = i & (TT-1);
  float c = ct[t*16+j], s = st[t*16+j];
  size_t base = (size_t)i*HH + h*32;
  float q1 = q[base+j], q2 = q[base+16+j];
  float k1 = k[base+j], k2 = k[base+16+j];
  float r1 = q1*c - q2*s, r2 = q1*s + q2*c;
  q[base+j]    = r1 > 0.f ? r1+1.f : expf(r1);
  q[base+16+j] = r2 > 0.f ? r2+1.f : expf(r2);
  r1 = k1*c - k2*s; r2 = k1*s + k2*c;
  k[base+j]    = r1 > 0.f ? r1+1.f : expf(r1);
  k[base+16+j] = r2 > 0.f ? r2+1.f : expf(r2);
}

// ---------------- chunked linear-attention scan ----------------
// One block per (b,h). Chunk L=64, 16 sequential chunks.
// A_ij = (q_i.k_j) * p_i/p_j (causal); num_i = p_i*(q_i^T S0) + sum_j A_ij v_j;
// den_i = p_i*(q_i.K0) + sum_j A_ij; state: S_L = pL*S0 + sum_j (pL/p_j) k_j v_j^T.
__global__ __launch_bounds__(256) void chunk_scan_k(
    const float* __restrict__ phi_q, const float* __restrict__ phi_k,
    const float* __restrict__ v, const float* __restrict__ braw,
    const float* __restrict__ mraw, float* __restrict__ y)
{
  __shared__ float Qs[64][36], Ks[64][36], Vs[64][36];
  __shared__ float A0[64][68];
  __shared__ float Sst[2][32][33];
  __shared__ float K0s[2][32];
  __shared__ float pbuf[2][64], ipbuf[2][64], wjs[2][64];
  __shared__ float bets[2][64], mixs[2][64], rdens[2][64];
  __shared__ float pLs[2];

  const int b = blockIdx.x >> 5, h = blockIdx.x & 31;
  const int tid = threadIdx.x;

  for (int u = tid; u < 2*32*33; u += 256) ((float*)Sst)[u] = 0.f;
  if (tid < 64) K0s[tid>>5][tid&31] = 0.f;
  __syncthreads();

  for (int ch = 0; ch < NCH; ++ch) {
    const int t0 = ch*CL;
    // ---- load chunk Q,K,V + fused beta/mix activation ----
    for (int u = tid; u < 512; u += 256) {
      int r = u >> 3, qq = u & 7;
      size_t src = (size_t)(b*TT + t0 + r)*HH + h*32 + qq*4;
      float4 qa = *reinterpret_cast<const float4*>(phi_q + src);
      float4 ka = *reinterpret_cast<const float4*>(phi_k + src);
      float4 va = *reinterpret_cast<const float4*>(v + src);
      *reinterpret_cast<float4*>(&Qs[r][qq*4]) = qa;
      *reinterpret_cast<float4*>(&Ks[r][qq*4]) = ka;
      *reinterpret_cast<float4*>(&Vs[r][qq*4]) = va;
    }
    if (tid < 64) {
      int tl = tid;
      int rowi = ((b*TT + t0 + tl)*NHH + h)*2;
      float b0 = sigmoidf_(braw[rowi]), b1 = sigmoidf_(braw[rowi+1]);
      bets[0][tl] = fminf(fmaxf(b0, 0.85f), 0.9995f);
      bets[1][tl] = fminf(fmaxf(b1, 0.85f), 0.9995f);
      float a0 = mraw[rowi], a1 = mraw[rowi+1];
      float mx = fmaxf(a0,a1);
      float e0 = expf(a0-mx), e1 = expf(a1-mx);
      float inv = 1.f/(e0+e1);
      mixs[0][tl] = e0*inv; mixs[1][tl] = e1*inv;
    }
    __syncthreads();

    // ---- inclusive cumulative-product scan of beta (waves 0,1) ----
    if (tid < 128) {
      int m = tid >> 6, lane = tid & 63;
      float p = bets[m][lane];
      #pragma unroll
      for (int off = 1; off < 64; off <<= 1) {
        float o = __shfl_up(p, off);
        if (lane >= off) p *= o;
      }
      pbuf[m][lane] = p;
      ipbuf[m][lane] = 1.f/p;
      if (lane == 63) pLs[m] = p;
    }
    __syncthreads();

    // ---- A0 = Q K^T (full 64x64, masked at consumption) ----
    {
      int i = tid >> 2, jb = (tid & 3) * 16;
      const float4* qrow = reinterpret_cast<const float4*>(&Qs[i][0]);
      for (int jj = 0; jj < 16; ++jj) {
        int j = jb + jj;
        const float4* krow = reinterpret_cast<const float4*>(&Ks[j][0]);
        float acc = 0.f;
        #pragma unroll
        for (int u = 0; u < 8; ++u) {
          float4 qa = qrow[u], ka = krow[u];
          acc = fmaf(qa.x,ka.x, fmaf(qa.y,ka.y, fmaf(qa.z,ka.z, fmaf(qa.w,ka.w, acc))));
        }
        A0[i][j] = acc;
      }
    }
    __syncthreads();

    // ---- den (+recip) and wj = pL/p_j ----
    if (tid < 128) {
      int m = tid & 1, i = tid >> 1;
      float qK0 = 0.f;
      #pragma unroll 8
      for (int d = 0; d < 32; ++d) qK0 = fmaf(Qs[i][d], K0s[m][d], qK0);
      float Bacc = 0.f;
      for (int j = 0; j <= i; ++j) Bacc = fmaf(A0[i][j], ipbuf[m][j], Bacc);
      float den = pbuf[m][i]*(qK0 + Bacc) + 1e-6f;
      rdens[m][i] = 1.f/den;
    } else {
      int u = tid - 128;
      int m = u & 1, j = u >> 1;
      wjs[m][j] = pLs[m]*ipbuf[m][j];
    }
    __syncthreads();

    // ---- num + y ----
    {
      int c = tid & 31, io = tid >> 5;
      for (int r = 0; r < 8; ++r) {
        int i = io + 8*r;
        float s0 = 0.f, s1 = 0.f;
        #pragma unroll 8
        for (int d = 0; d < 32; ++d) {
          float qd = Qs[i][d];
          s0 = fmaf(qd, Sst[0][d][c], s0);
          s1 = fmaf(qd, Sst[1][d][c], s1);
        }
        float a0acc = 0.f, a1acc = 0.f;
        for (int j = 0; j <= i; ++j) {
          float a = A0[i][j], vv = Vs[j][c];
          a0acc = fmaf(a*ipbuf[0][j], vv, a0acc);
          a1acc = fmaf(a*ipbuf[1][j], vv, a1acc);
        }
        float n0 = pbuf[0][i]*(s0 + a0acc);
        float n1 = pbuf[1][i]*(s1 + a1acc);
        float yv = mixs[0][i]*n0*rdens[0][i] + mixs[1][i]*n1*rdens[1][i];
        y[(size_t)(b*TT + t0 + i)*HH + h*32 + c] = yv;
      }
    }
    __syncthreads();

    // ---- state update: S = pL*S + sum_j wj k_j v_j^T ; K0 = pL*K0 + sum_j wj k_j ----
    {
      int c = tid & 31, dg = tid >> 5;
      float pL0 = pLs[0], pL1 = pLs[1];
      #pragma unroll
      for (int dd = 0; dd < 4; ++dd) {
        int d = dg + 8*dd;
        float acc0 = 0.f, acc1 = 0.f;
        for (int j = 0; j < 64; ++j) {
          float kv = Ks[j][d]*Vs[j][c];
          acc0 = fmaf(wjs[0][j], kv, acc0);
          acc1 = fmaf(wjs[1][j], kv, acc1);
        }
        Sst[0][d][c] = fmaf(pL0, Sst[0][d][c], acc0);
        Sst[1][d][c] = fmaf(pL1, Sst[1][d][c], acc1);
      }
      if (tid < 64) {
        int m = tid >> 5, d = tid & 31;
        float acc = 0.f;
        for (int j = 0; j < 64; ++j) acc = fmaf(wjs[m][j], Ks[j][d], acc);
        K0s[m][d] = fmaf(pLs[m], K0s[m][d], acc);
      }
    }
    __syncthreads();
  }
}

// ---------------- LayerNorm over rows of 1024 ----------------
__global__ __launch_bounds__(256) void ln_k(
    const float* __restrict__ z, const float* __restrict__ g,
    const float* __restrict__ bta, float* __restrict__ out)
{
  const int row = blockIdx.x;
  const int tid = threadIdx.x;
  const float* zr = z + (size_t)row*HH;
  float4 zv = reinterpret_cast<const float4*>(zr)[tid];
  float sum = zv.x+zv.y+zv.z+zv.w;
  float sq  = zv.x*zv.x + zv.y*zv.y + zv.z*zv.z + zv.w*zv.w;
  #pragma unroll
  for (int off=1; off<64; off<<=1){ sum += __shfl_xor(sum, off); sq += __shfl_xor(sq, off); }
  __shared__ float s1[4], s2[4];
  int w = tid>>6;
  if ((tid&63)==0){ s1[w]=sum; s2[w]=sq; }
  __syncthreads();
  sum = s1[0]+s1[1]+s1[2]+s1[3];
  sq  = s2[0]+s2[1]+s2[2]+s2[3];
  float mu  = sum * (1.f/1024.f);
  float var = sq * (1.f/1024.f) - mu*mu;
  float rstd = rsqrtf(var + 1e-5f);
  float4 gv = reinterpret_cast<const float4*>(g)[tid];
  float4 bv = reinterpret_cast<const float4*>(bta)[tid];
  float4 ov;
  ov.x = (zv.x-mu)*rstd*gv.x + bv.x;
  ov.y = (zv.y-mu)*rstd*gv.y + bv.y;
  ov.z = (zv.z-mu)*rstd*gv.z + bv.z;
  ov.w = (zv.w-mu)*rstd*gv.w + bv.w;
  reinterpret_cast<float4*>(out + (size_t)row*HH)[tid] = ov;
}

extern "C" void kernel_launch(void* const* d_in, const int* in_sizes, int n_in,
                              void* d_out, int out_size, void* d_ws, size_t ws_size,
                              hipStream_t stream)
{
  const float* x     = (const float*)d_in[0];
  const float* Wq    = (const float*)d_in[1];
  const float* Wk    = (const float*)d_in[2];
  const float* Wv    = (const float*)d_in[3];
  const float* Wbeta = (const float*)d_in[4];
  const float* bbeta = (const float*)d_in[5];
  const float* Wmix  = (const float*)d_in[6];
  const float* bmix  = (const float*)d_in[7];
  const float* Wout  = (const float*)d_in[8];
  const float* bout  = (const float*)d_in[9];
  const float* ln_g  = (const float*)d_in[10];
  const float* ln_b  = (const float*)d_in[11];
  float* out = (float*)d_out;

  float* ws = (float*)d_ws;
  float* ct   = ws;                  // 16384
  float* st   = ct + 16384;          // 16384
  float* qraw = st + 16384;          // 4194304  (becomes phi_q in place)
  float* kraw = qraw + 4194304;      // 4194304  (becomes phi_k in place)
  float* vraw = kraw + 4194304;      // 4194304  (reused as z after scan)
  float* braw = vraw + 4194304;      // 262144
  float* mraw = braw + 262144;       // 262144
  float* y    = mraw + 262144;       // 4194304
  float* z    = vraw;

  rope_table_k<<<64, 256, 0, stream>>>(ct, st);
  dim3 g16(16, 64), g1(1, 64);
  gemm_bt_k<<<g16, 256, 0, stream>>>(x, Wq,    nullptr, nullptr, qraw, 1024, 1024);
  gemm_bt_k<<<g16, 256, 0, stream>>>(x, Wk,    nullptr, nullptr, kraw, 1024, 1024);
  gemm_bt_k<<<g16, 256, 0, stream>>>(x, Wv,    nullptr, nullptr, vraw, 1024, 1024);
  gemm_bt_k<<<g1,  256, 0, stream>>>(x, Wbeta, bbeta,   nullptr, braw,   64, 1024);
  gemm_bt_k<<<g1,  256, 0, stream>>>(x, Wmix,  bmix,    nullptr, mraw,   64, 1024);
  rope_phi_k<<<8192, 256, 0, stream>>>(qraw, kraw, ct, st);
  chunk_scan_k<<<128, 256, 0, stream>>>(qraw, kraw, vraw, braw, mraw, y);
  gemm_bt_k<<<g16, 256, 0, stream>>>(y, Wout, bout, x, z, 1024, 1024);
  ln_k<<<4096, 256, 0, stream>>>(z, ln_g, ln_b, out);
}

// Round 3
// 459.803 us; speedup vs baseline: 3.4634x; 2.5528x over previous
//
#include <hip/hip_runtime.h>
#include <math.h>

#define TT 1024
#define BB 4
#define HH 1024
#define NHH 32
#define CL 64
#define NCH (TT/CL)

typedef unsigned short u16;
typedef __attribute__((ext_vector_type(8))) short short8;
typedef __attribute__((ext_vector_type(8))) unsigned short u16x8;
typedef __attribute__((ext_vector_type(4))) float floatx4;

__device__ __forceinline__ float sigmoidf_(float x){ return 1.f/(1.f+expf(-x)); }
__device__ __forceinline__ u16 f2b(float f){
  union { float f; unsigned u; } x; x.f = f;
  unsigned r = x.u + 0x7FFFu + ((x.u >> 16) & 1u);
  return (u16)(r >> 16);
}
__device__ __forceinline__ float b2f(u16 v){
  union { unsigned u; float f; } x; x.u = ((unsigned)v) << 16;
  return x.f;
}

// ---------------- cast fp32 -> bf16 for x and all weights ----------------
__global__ __launch_bounds__(256) void cast_all_k(
    const float* __restrict__ x, const float* __restrict__ Wq, const float* __restrict__ Wk,
    const float* __restrict__ Wv, const float* __restrict__ Wout,
    const float* __restrict__ Wbeta, const float* __restrict__ Wmix,
    u16* __restrict__ x_bf, u16* __restrict__ Wq_bf, u16* __restrict__ Wk_bf,
    u16* __restrict__ Wv_bf, u16* __restrict__ Wout_bf, u16* __restrict__ Wbm_bf)
{
  size_t v = (size_t)blockIdx.x*256 + threadIdx.x;
  size_t e = v*4;
  const float* src; u16* dst; size_t so, dof;
  if      (e < 4194304) { src=x;     dst=x_bf;    so=e;          dof=so; }
  else if (e < 5242880) { src=Wq;    dst=Wq_bf;   so=e-4194304;  dof=so; }
  else if (e < 6291456) { src=Wk;    dst=Wk_bf;   so=e-5242880;  dof=so; }
  else if (e < 7340032) { src=Wv;    dst=Wv_bf;   so=e-6291456;  dof=so; }
  else if (e < 8388608) { src=Wout;  dst=Wout_bf; so=e-7340032;  dof=so; }
  else if (e < 8454144) { src=Wbeta; dst=Wbm_bf;  so=e-8388608;  dof=so; }
  else                  { src=Wmix;  dst=Wbm_bf;  so=e-8454144;  dof=so+65536; }
  float4 f = *reinterpret_cast<const float4*>(src + so);
  ushort4 u; u.x=f2b(f.x); u.y=f2b(f.y); u.z=f2b(f.z); u.w=f2b(f.w);
  *reinterpret_cast<ushort4*>(dst + dof) = u;
}

// ---------------- RoPE cos/sin table: ct/st[t*16+j] ----------------
__global__ __launch_bounds__(256) void rope_table_k(float* __restrict__ ct, float* __restrict__ st){
  int idx = blockIdx.x*256 + threadIdx.x;   // 16384
  int t = idx >> 4, j = idx & 15;
  float invf = powf(10000.f, -(float)j/16.f);
  float ang = (float)t * invf;
  ct[idx] = cosf(ang);
  st[idx] = sinf(ang);
}

// ---------------- bf16 MFMA GEMM: C[4096,N] = A @ W^T (+bias)(+res) ----------------
// 128x128 tile, BK=64, 4 waves (2x2), global_load_lds(16B) with XOR chunk swizzle.
__global__ __launch_bounds__(256) void gemm_mfma_k(
    const u16* __restrict__ A, const u16* __restrict__ W,
    const float* __restrict__ bias, const float* __restrict__ res,
    float* __restrict__ Cf, u16* __restrict__ Cb, int N, int K)
{
  __shared__ u16 As[128*64];
  __shared__ u16 Ws[128*64];
  const int tid = threadIdx.x;
  const int lane = tid & 63;
  const int wave = tid >> 6;
  const int wm = wave >> 1, wn = wave & 1;
  const int row0 = blockIdx.y*128, col0 = blockIdx.x*128;
  const int lr = lane & 15, lkg = lane >> 4;   // frag row / k-group

  floatx4 acc[4][4];
  #pragma unroll
  for (int mt=0; mt<4; ++mt)
    #pragma unroll
    for (int nt=0; nt<4; ++nt)
      acc[mt][nt] = (floatx4){0.f,0.f,0.f,0.f};

  for (int k0 = 0; k0 < K; k0 += 64) {
    __syncthreads();
    #pragma unroll
    for (int it = 0; it < 4; ++it) {
      int li  = it*256 + tid;
      int row = li >> 3, ckp = li & 7;
      int ck  = ckp ^ (row & 7);
      const u16* ga = A + (size_t)(row0+row)*K + k0 + ck*8;
      const u16* gw = W + (size_t)(col0+row)*K + k0 + ck*8;
      __builtin_amdgcn_global_load_lds(
          (const __attribute__((address_space(1))) void*)ga,
          (__attribute__((address_space(3))) void*)(As + (size_t)(li & ~63)*8), 16, 0, 0);
      __builtin_amdgcn_global_load_lds(
          (const __attribute__((address_space(1))) void*)gw,
          (__attribute__((address_space(3))) void*)(Ws + (size_t)(li & ~63)*8), 16, 0, 0);
    }
    __syncthreads();
    #pragma unroll
    for (int kk = 0; kk < 64; kk += 32) {
      short8 af[4], wf[4];
      const int ckw = (kk >> 3) + lkg;
      #pragma unroll
      for (int t = 0; t < 4; ++t) {
        int rowA = wm*64 + t*16 + lr;
        int rowW = wn*64 + t*16 + lr;
        af[t] = *reinterpret_cast<const short8*>(As + rowA*64 + (ckw ^ (rowA & 7))*8);
        wf[t] = *reinterpret_cast<const short8*>(Ws + rowW*64 + (ckw ^ (rowW & 7))*8);
      }
      #pragma unroll
      for (int mt = 0; mt < 4; ++mt)
        #pragma unroll
        for (int nt = 0; nt < 4; ++nt)
          acc[mt][nt] = __builtin_amdgcn_mfma_f32_16x16x32_bf16(af[mt], wf[nt], acc[mt][nt], 0, 0, 0);
    }
  }
  // epilogue: D row=(lane>>4)*4+r, col=lane&15
  #pragma unroll
  for (int mt = 0; mt < 4; ++mt) {
    #pragma unroll
    for (int r = 0; r < 4; ++r) {
      int row = row0 + wm*64 + mt*16 + lkg*4 + r;
      #pragma unroll
      for (int nt = 0; nt < 4; ++nt) {
        int col = col0 + wn*64 + nt*16 + lr;
        float v = acc[mt][nt][r];
        if (bias) v += bias[col];
        if (res)  v += res[(size_t)row*N + col];
        if (Cb) Cb[(size_t)row*N + col] = f2b(v);
        else    Cf[(size_t)row*N + col] = v;
      }
    }
  }
}

// ---------------- RoPE + (elu+1), in place on bf16 q/k ----------------
__global__ __launch_bounds__(256) void rope_phi_k(
    u16* __restrict__ q, u16* __restrict__ k,
    const float* __restrict__ ct, const float* __restrict__ st)
{
  int idx = blockIdx.x*256 + threadIdx.x;   // 2097152
  int i = idx >> 9;
  int h = (idx >> 4) & 31;
  int j = idx & 15;
  int t = i & (TT-1);
  float c = ct[t*16+j], s = st[t*16+j];
  size_t base = (size_t)i*HH + h*32;
  float q1 = b2f(q[base+j]), q2 = b2f(q[base+16+j]);
  float k1 = b2f(k[base+j]), k2 = b2f(k[base+16+j]);
  float r1 = q1*c - q2*s, r2 = q1*s + q2*c;
  q[base+j]    = f2b(r1 > 0.f ? r1+1.f : expf(r1));
  q[base+16+j] = f2b(r2 > 0.f ? r2+1.f : expf(r2));
  r1 = k1*c - k2*s; r2 = k1*s + k2*c;
  k[base+j]    = f2b(r1 > 0.f ? r1+1.f : expf(r1));
  k[base+16+j] = f2b(r2 > 0.f ? r2+1.f : expf(r2));
}

// ---------------- scan pass 1: per-chunk state deltas ----------------
// grid (ch=16, h=32, b=4), 256 thr. dS[bh][ch][m][d][c], dK[bh][ch][m][d], pL, p.
__global__ __launch_bounds__(256) void scan_delta_k(
    const u16* __restrict__ kb, const u16* __restrict__ vb,
    const float* __restrict__ bmraw, const float* __restrict__ bbeta,
    float* __restrict__ dS, float* __restrict__ dK,
    float* __restrict__ pLg, float* __restrict__ pg)
{
  __shared__ float Ks[64][36], Vs[64][36];
  __shared__ float bets[2][64];
  __shared__ float pbuf[2][64], wjs[2][64];
  __shared__ float pLs[2];
  const int ch = blockIdx.x, h = blockIdx.y, b = blockIdx.z;
  const int bh = b*NHH + h;
  const int tid = threadIdx.x;
  const int t0 = ch*CL;
  {
    int r = tid >> 2, ck = tid & 3;
    size_t src = (size_t)(b*TT + t0 + r)*HH + h*32 + ck*8;
    u16x8 uk = *reinterpret_cast<const u16x8*>(kb + src);
    u16x8 uv = *reinterpret_cast<const u16x8*>(vb + src);
    #pragma unroll
    for (int jj = 0; jj < 8; ++jj) {
      Ks[r][ck*8+jj] = b2f(uk[jj]);
      Vs[r][ck*8+jj] = b2f(uv[jj]);
    }
  }
  if (tid < 128) {
    int m = tid & 1, tl = tid >> 1;
    float braw_v = bmraw[(size_t)(b*TT + t0 + tl)*128 + h*2 + m] + bbeta[h*2+m];
    bets[m][tl] = fminf(fmaxf(sigmoidf_(braw_v), 0.85f), 0.9995f);
  }
  __syncthreads();
  if (tid < 128) {
    int m = tid >> 6, lane2 = tid & 63;
    float p = bets[m][lane2];
    #pragma unroll
    for (int off = 1; off < 64; off <<= 1) {
      float o = __shfl_up(p, off);
      if (lane2 >= off) p *= o;
    }
    pbuf[m][lane2] = p;
    if (lane2 == 63) pLs[m] = p;
  }
  __syncthreads();
  if (tid < 128) {
    int m = tid >> 6, j = tid & 63;
    wjs[m][j] = pLs[m] / pbuf[m][j];
    pg[(((size_t)bh*NCH + ch)*2 + m)*64 + j] = pbuf[m][j];
  }
  __syncthreads();
  {
    const int c = tid & 31, dg = tid >> 5;
    #pragma unroll
    for (int dd = 0; dd < 4; ++dd) {
      int d = dg + 8*dd;
      float a0 = 0.f, a1 = 0.f;
      for (int j = 0; j < 64; ++j) {
        float kv = Ks[j][d]*Vs[j][c];
        a0 = fmaf(wjs[0][j], kv, a0);
        a1 = fmaf(wjs[1][j], kv, a1);
      }
      size_t o = (((size_t)bh*NCH + ch)*2)*1024 + d*32 + c;
      dS[o] = a0; dS[o + 1024] = a1;
    }
  }
  if (tid < 64) {
    int m = tid >> 5, d = tid & 31;
    float a = 0.f;
    for (int j = 0; j < 64; ++j) a = fmaf(wjs[m][j], Ks[j][d], a);
    dK[(((size_t)bh*NCH + ch)*2 + m)*32 + d] = a;
  }
  if (tid < 2) pLg[(((size_t)bh*NCH + ch)*2) + tid] = pLs[tid];
}

// ---------------- scan pass 2: in-place prefix scan of states across chunks ----------------
// grid 256 = (bh,m); 1024 thr = (d,c). buf[ch] := prefix-before; carry = pL*carry + delta.
__global__ __launch_bounds__(1024) void scan_state_k(
    float* dSS0, float* dKK0, const float* __restrict__ pLg)
{
  const int bhm = blockIdx.x;
  const int bh = bhm >> 1, m = bhm & 1;
  const int tid = threadIdx.x;
  float S = 0.f, K0 = 0.f;
  for (int ch = 0; ch < NCH; ++ch) {
    float pl = pLg[((size_t)bh*NCH + ch)*2 + m];
    size_t o = (((size_t)bh*NCH + ch)*2 + m)*1024 + tid;
    float d = dSS0[o];
    dSS0[o] = S;
    S = fmaf(pl, S, d);
    if (tid < 32) {
      size_t ok = (((size_t)bh*NCH + ch)*2 + m)*32 + tid;
      float dk = dKK0[ok];
      dKK0[ok] = K0;
      K0 = fmaf(pl, K0, dk);
    }
  }
}

// ---------------- scan pass 3: apply (recompute A0, produce y in bf16) ----------------
__global__ __launch_bounds__(256) void scan_apply_k(
    const u16* __restrict__ qb, const u16* __restrict__ kb, const u16* __restrict__ vb,
    const float* __restrict__ bmraw, const float* __restrict__ bbeta, const float* __restrict__ bmix,
    const float* __restrict__ S0g, const float* __restrict__ K0g,
    const float* __restrict__ pg, u16* __restrict__ yb)
{
  __shared__ float Qs[64][36], Ks[64][36], Vs[64][36];
  __shared__ float A0[64][65];
  __shared__ float S0s[2][32][33];
  __shared__ float K0s[2][32];
  __shared__ float pbv[2][64], ipb[2][64];
  __shared__ float mixs[2][64], rdens[2][64];
  const int ch = blockIdx.x, h = blockIdx.y, b = blockIdx.z;
  const int bh = b*NHH + h;
  const int tid = threadIdx.x;
  const int t0 = ch*CL;
  {
    int r = tid >> 2, ck = tid & 3;
    size_t src = (size_t)(b*TT + t0 + r)*HH + h*32 + ck*8;
    u16x8 uq = *reinterpret_cast<const u16x8*>(qb + src);
    u16x8 uk = *reinterpret_cast<const u16x8*>(kb + src);
    u16x8 uv = *reinterpret_cast<const u16x8*>(vb + src);
    #pragma unroll
    for (int jj = 0; jj < 8; ++jj) {
      Qs[r][ck*8+jj] = b2f(uq[jj]);
      Ks[r][ck*8+jj] = b2f(uk[jj]);
      Vs[r][ck*8+jj] = b2f(uv[jj]);
    }
  }
  for (int u = tid; u < 2048; u += 256) {
    int m = u >> 10, d = (u >> 5) & 31, c = u & 31;
    S0s[m][d][c] = S0g[(((size_t)bh*NCH + ch)*2 + m)*1024 + (u & 1023)];
  }
  if (tid < 64) {
    int m = tid >> 5, d = tid & 31;
    K0s[m][d] = K0g[(((size_t)bh*NCH + ch)*2 + m)*32 + d];
  }
  if (tid < 128) {
    int m = tid & 1, tl = tid >> 1;
    float p = pg[(((size_t)bh*NCH + ch)*2 + m)*64 + tl];
    pbv[m][tl] = p;
    ipb[m][tl] = 1.f/p;
  } else if (tid < 192) {
    int tl = tid - 128;
    size_t rb = (size_t)(b*TT + t0 + tl)*128 + 64 + h*2;
    float a0 = bmraw[rb]   + bmix[h*2];
    float a1 = bmraw[rb+1] + bmix[h*2+1];
    float mx = fmaxf(a0, a1);
    float e0 = expf(a0-mx), e1 = expf(a1-mx);
    float inv = 1.f/(e0+e1);
    mixs[0][tl] = e0*inv; mixs[1][tl] = e1*inv;
  }
  __syncthreads();
  // A0 = Q K^T
  {
    int i = tid >> 2, jlo = tid & 3;
    const float4* qrow = reinterpret_cast<const float4*>(&Qs[i][0]);
    for (int jj = 0; jj < 16; ++jj) {
      int j = jlo + 4*jj;
      const float4* krow = reinterpret_cast<const float4*>(&Ks[j][0]);
      float acc = 0.f;
      #pragma unroll
      for (int u = 0; u < 8; ++u) {
        float4 qa = qrow[u], ka = krow[u];
        acc = fmaf(qa.x,ka.x, fmaf(qa.y,ka.y, fmaf(qa.z,ka.z, fmaf(qa.w,ka.w, acc))));
      }
      A0[i][j] = acc;
    }
  }
  __syncthreads();
  // dens
  if (tid < 128) {
    int m = tid & 1, i = tid >> 1;
    float qK0 = 0.f;
    #pragma unroll 8
    for (int d = 0; d < 32; ++d) qK0 = fmaf(Qs[i][d], K0s[m][d], qK0);
    float Bacc = 0.f;
    for (int j = 0; j <= i; ++j) Bacc = fmaf(A0[i][j], ipb[m][j], Bacc);
    float den = pbv[m][i]*(qK0 + Bacc) + 1e-6f;
    rdens[m][i] = 1.f/den;
  }
  __syncthreads();
  // y
  {
    int c = tid & 31, io = tid >> 5;
    for (int r = 0; r < 8; ++r) {
      int i = io + 8*r;
      float s0 = 0.f, s1 = 0.f;
      #pragma unroll 8
      for (int d = 0; d < 32; ++d) {
        float qd = Qs[i][d];
        s0 = fmaf(qd, S0s[0][d][c], s0);
        s1 = fmaf(qd, S0s[1][d][c], s1);
      }
      float a0acc = 0.f, a1acc = 0.f;
      for (int j = 0; j <= i; ++j) {
        float a = A0[i][j], vv = Vs[j][c];
        a0acc = fmaf(a*ipb[0][j], vv, a0acc);
        a1acc = fmaf(a*ipb[1][j], vv, a1acc);
      }
      float n0 = pbv[0][i]*(s0 + a0acc);
      float n1 = pbv[1][i]*(s1 + a1acc);
      float yv = mixs[0][i]*n0*rdens[0][i] + mixs[1][i]*n1*rdens[1][i];
      yb[(size_t)(b*TT + t0 + i)*HH + h*32 + c] = f2b(yv);
    }
  }
}

// ---------------- LayerNorm over rows of 1024 ----------------
__global__ __launch_bounds__(256) void ln_k(
    const float* __restrict__ z, const float* __restrict__ g,
    const float* __restrict__ bta, float* __restrict__ out)
{
  const int row = blockIdx.x;
  const int tid = threadIdx.x;
  const float* zr = z + (size_t)row*HH;
  float4 zv = reinterpret_cast<const float4*>(zr)[tid];
  float sum = zv.x+zv.y+zv.z+zv.w;
  float sq  = zv.x*zv.x + zv.y*zv.y + zv.z*zv.z + zv.w*zv.w;
  #pragma unroll
  for (int off=1; off<64; off<<=1){ sum += __shfl_xor(sum, off); sq += __shfl_xor(sq, off); }
  __shared__ float s1[4], s2[4];
  int w = tid>>6;
  if ((tid&63)==0){ s1[w]=sum; s2[w]=sq; }
  __syncthreads();
  sum = s1[0]+s1[1]+s1[2]+s1[3];
  sq  = s2[0]+s2[1]+s2[2]+s2[3];
  float mu  = sum * (1.f/1024.f);
  float var = sq * (1.f/1024.f) - mu*mu;
  float rstd = rsqrtf(var + 1e-5f);
  float4 gv = reinterpret_cast<const float4*>(g)[tid];
  float4 bv = reinterpret_cast<const float4*>(bta)[tid];
  float4 ov;
  ov.x = (zv.x-mu)*rstd*gv.x + bv.x;
  ov.y = (zv.y-mu)*rstd*gv.y + bv.y;
  ov.z = (zv.z-mu)*rstd*gv.z + bv.z;
  ov.w = (zv.w-mu)*rstd*gv.w + bv.w;
  reinterpret_cast<float4*>(out + (size_t)row*HH)[tid] = ov;
}

extern "C" void kernel_launch(void* const* d_in, const int* in_sizes, int n_in,
                              void* d_out, int out_size, void* d_ws, size_t ws_size,
                              hipStream_t stream)
{
  const float* x     = (const float*)d_in[0];
  const float* Wq    = (const float*)d_in[1];
  const float* Wk    = (const float*)d_in[2];
  const float* Wv    = (const float*)d_in[3];
  const float* Wbeta = (const float*)d_in[4];
  const float* bbeta = (const float*)d_in[5];
  const float* Wmix  = (const float*)d_in[6];
  const float* bmix  = (const float*)d_in[7];
  const float* Wout  = (const float*)d_in[8];
  const float* bout  = (const float*)d_in[9];
  const float* ln_g  = (const float*)d_in[10];
  const float* ln_b  = (const float*)d_in[11];
  float* out = (float*)d_out;

  float* ws = (float*)d_ws;
  // layout (float offsets):
  float* ct      = ws;                       // 16384
  float* st      = ws + 16384;               // 16384
  u16*   x_bf    = (u16*)(ws + 32768);       // 4194304 u16 (reused as y_bf)
  u16*   Wq_bf   = (u16*)(ws + 2129920);     // 1048576 u16
  u16*   Wk_bf   = (u16*)(ws + 2654208);
  u16*   Wv_bf   = (u16*)(ws + 3178496);
  u16*   Wout_bf = (u16*)(ws + 3702784);
  u16*   Wbm_bf  = (u16*)(ws + 4227072);     // 131072 u16
  u16*   q_bf    = (u16*)(ws + 4292608);     // 4194304 u16
  u16*   k_bf    = (u16*)(ws + 6389760);
  u16*   v_bf    = (u16*)(ws + 8486912);
  float* bmraw   = ws + 10584064;            // 524288
  float* dSS0    = ws + 11108352;            // 4194304 (reused as z)
  float* dKK0    = ws + 15302656;            // 131072
  float* pLg     = ws + 15433728;            // 4096
  float* pg      = ws + 15437824;            // 262144
  u16*   y_bf    = x_bf;
  float* z       = dSS0;

  cast_all_k<<<8320, 256, 0, stream>>>(x, Wq, Wk, Wv, Wout, Wbeta, Wmix,
                                       x_bf, Wq_bf, Wk_bf, Wv_bf, Wout_bf, Wbm_bf);
  rope_table_k<<<64, 256, 0, stream>>>(ct, st);
  dim3 g1024(8, 32), g128(1, 32);
  gemm_mfma_k<<<g1024, 256, 0, stream>>>(x_bf, Wq_bf, nullptr, nullptr, nullptr, q_bf, 1024, 1024);
  gemm_mfma_k<<<g1024, 256, 0, stream>>>(x_bf, Wk_bf, nullptr, nullptr, nullptr, k_bf, 1024, 1024);
  gemm_mfma_k<<<g1024, 256, 0, stream>>>(x_bf, Wv_bf, nullptr, nullptr, nullptr, v_bf, 1024, 1024);
  gemm_mfma_k<<<g128,  256, 0, stream>>>(x_bf, Wbm_bf, nullptr, nullptr, bmraw, nullptr, 128, 1024);
  rope_phi_k<<<8192, 256, 0, stream>>>(q_bf, k_bf, ct, st);
  dim3 gscan(NCH, 32, 4);
  scan_delta_k<<<gscan, 256, 0, stream>>>(k_bf, v_bf, bmraw, bbeta, dSS0, dKK0, pLg, pg);
  scan_state_k<<<256, 1024, 0, stream>>>(dSS0, dKK0, pLg);
  scan_apply_k<<<gscan, 256, 0, stream>>>(q_bf, k_bf, v_bf, bmraw, bbeta, bmix,
                                          dSS0, dKK0, pg, y_bf);
  gemm_mfma_k<<<g1024, 256, 0, stream>>>(y_bf, Wout_bf, bout, x, z, nullptr, 1024, 1024);
  ln_k<<<4096, 256, 0, stream>>>(z, ln_g, ln_b, out);
}

// Round 4
// 237.924 us; speedup vs baseline: 6.6931x; 1.9326x over previous
//
#include <hip/hip_runtime.h>
#include <math.h>

#define TT 1024
#define BB 4
#define HH 1024
#define NHH 32
#define CL 64
#define NCH (TT/CL)

typedef unsigned short u16;
typedef __attribute__((ext_vector_type(8))) short short8;
typedef __attribute__((ext_vector_type(8))) unsigned short u16x8;
typedef __attribute__((ext_vector_type(4))) float floatx4;

__device__ __forceinline__ float sigmoidf_(float x){ return 1.f/(1.f+expf(-x)); }
__device__ __forceinline__ u16 f2b(float f){
  union { float f; unsigned u; } x; x.f = f;
  unsigned r = x.u + 0x7FFFu + ((x.u >> 16) & 1u);
  return (u16)(r >> 16);
}
__device__ __forceinline__ float b2f(u16 v){
  union { unsigned u; float f; } x; x.u = ((unsigned)v) << 16;
  return x.f;
}

// ---------------- cast fp32 -> bf16: x, fused [Wq|Wk|Wv|Wbeta|Wmix], Wout ----------------
__global__ __launch_bounds__(256) void cast_all_k(
    const float* __restrict__ x, const float* __restrict__ Wq, const float* __restrict__ Wk,
    const float* __restrict__ Wv, const float* __restrict__ Wbeta, const float* __restrict__ Wmix,
    const float* __restrict__ Wout,
    u16* __restrict__ x_bf, u16* __restrict__ Wf, u16* __restrict__ Wout_bf)
{
  size_t e = ((size_t)blockIdx.x*256 + threadIdx.x)*4;   // 8519680 total elems
  const float* src; u16* dst; size_t so, dof;
  if      (e < 4194304) { src=x;     dst=x_bf;    so=e;          dof=so; }
  else if (e < 5242880) { src=Wq;    dst=Wf;      so=e-4194304;  dof=so; }
  else if (e < 6291456) { src=Wk;    dst=Wf;      so=e-5242880;  dof=so+1048576; }
  else if (e < 7340032) { src=Wv;    dst=Wf;      so=e-6291456;  dof=so+2097152; }
  else if (e < 7405568) { src=Wbeta; dst=Wf;      so=e-7340032;  dof=so+3145728; }
  else if (e < 7471104) { src=Wmix;  dst=Wf;      so=e-7405568;  dof=so+3211264; }
  else                  { src=Wout;  dst=Wout_bf; so=e-7471104;  dof=so; }
  float4 f = *reinterpret_cast<const float4*>(src + so);
  ushort4 u; u.x=f2b(f.x); u.y=f2b(f.y); u.z=f2b(f.z); u.w=f2b(f.w);
  *reinterpret_cast<ushort4*>(dst + dof) = u;
}

// ---------------- RoPE cos/sin table ----------------
__global__ __launch_bounds__(256) void rope_table_k(float* __restrict__ ct, float* __restrict__ st){
  int idx = blockIdx.x*256 + threadIdx.x;   // 16384
  int t = idx >> 4, j = idx & 15;
  float invf = powf(10000.f, -(float)j/16.f);
  float ang = (float)t * invf;
  ct[idx] = cosf(ang);
  st[idx] = sinf(ang);
}

// ---------------- fused QKV+beta/mix GEMM, N=3200, rope+elu epilogue ----------------
__global__ __launch_bounds__(256) void gemm_qkv_k(
    const u16* __restrict__ A, const u16* __restrict__ W,
    const float* __restrict__ ct, const float* __restrict__ st,
    u16* __restrict__ qkv, float* __restrict__ bmraw)
{
  __shared__ u16 As[128*64];
  __shared__ u16 Ws[128*64];
  const int tid = threadIdx.x;
  const int lane = tid & 63;
  const int wave = tid >> 6;
  const int wm = wave >> 1, wn = wave & 1;
  const int row0 = blockIdx.y*128, col0 = blockIdx.x*128;
  const int lr = lane & 15, lkg = lane >> 4;

  floatx4 acc[4][4];
  #pragma unroll
  for (int mt=0; mt<4; ++mt)
    #pragma unroll
    for (int nt=0; nt<4; ++nt)
      acc[mt][nt] = (floatx4){0.f,0.f,0.f,0.f};

  for (int k0 = 0; k0 < 1024; k0 += 64) {
    __syncthreads();
    #pragma unroll
    for (int it = 0; it < 4; ++it) {
      int li  = it*256 + tid;
      int row = li >> 3, ckp = li & 7;
      int ck  = ckp ^ (row & 7);
      const u16* ga = A + (size_t)(row0+row)*1024 + k0 + ck*8;
      const u16* gw = W + (size_t)(col0+row)*1024 + k0 + ck*8;
      __builtin_amdgcn_global_load_lds(
          (const __attribute__((address_space(1))) void*)ga,
          (__attribute__((address_space(3))) void*)(As + (size_t)(li & ~63)*8), 16, 0, 0);
      __builtin_amdgcn_global_load_lds(
          (const __attribute__((address_space(1))) void*)gw,
          (__attribute__((address_space(3))) void*)(Ws + (size_t)(li & ~63)*8), 16, 0, 0);
    }
    __syncthreads();
    #pragma unroll
    for (int kk = 0; kk < 64; kk += 32) {
      short8 af[4], wf[4];
      const int ckw = (kk >> 3) + lkg;
      #pragma unroll
      for (int t = 0; t < 4; ++t) {
        int rowA = wm*64 + t*16 + lr;
        int rowW = wn*64 + t*16 + lr;
        af[t] = *reinterpret_cast<const short8*>(As + rowA*64 + (ckw ^ (rowA & 7))*8);
        wf[t] = *reinterpret_cast<const short8*>(Ws + rowW*64 + (ckw ^ (rowW & 7))*8);
      }
      #pragma unroll
      for (int mt = 0; mt < 4; ++mt)
        #pragma unroll
        for (int nt = 0; nt < 4; ++nt)
          acc[mt][nt] = __builtin_amdgcn_mfma_f32_16x16x32_bf16(af[mt], wf[nt], acc[mt][nt], 0, 0, 0);
    }
  }
  const int bx = blockIdx.x;
  if (bx < 16) {
    // q/k region: rope + elu+1.  d = 16*(nt&1)+lr; pairs (nt even, nt+1).
    #pragma unroll
    for (int mt = 0; mt < 4; ++mt) {
      #pragma unroll
      for (int r = 0; r < 4; ++r) {
        int row = row0 + wm*64 + mt*16 + lkg*4 + r;
        int t = row & (TT-1);
        float c_ = ct[t*16 + lr], s_ = st[t*16 + lr];
        #pragma unroll
        for (int nt = 0; nt < 4; nt += 2) {
          float u1 = acc[mt][nt][r], u2 = acc[mt][nt+1][r];
          float r1 = u1*c_ - u2*s_;
          float r2 = u1*s_ + u2*c_;
          r1 = r1 > 0.f ? r1+1.f : expf(r1);
          r2 = r2 > 0.f ? r2+1.f : expf(r2);
          int col = col0 + wn*64 + nt*16 + lr;
          qkv[(size_t)row*3072 + col]      = f2b(r1);
          qkv[(size_t)row*3072 + col + 16] = f2b(r2);
        }
      }
    }
  } else if (bx < 24) {
    // v region: passthrough bf16
    #pragma unroll
    for (int mt = 0; mt < 4; ++mt)
      #pragma unroll
      for (int r = 0; r < 4; ++r) {
        int row = row0 + wm*64 + mt*16 + lkg*4 + r;
        #pragma unroll
        for (int nt = 0; nt < 4; ++nt) {
          int col = col0 + wn*64 + nt*16 + lr;
          qkv[(size_t)row*3072 + col] = f2b(acc[mt][nt][r]);
        }
      }
  } else {
    // beta/mix raw fp32 -> bmraw[row][0..127]
    #pragma unroll
    for (int mt = 0; mt < 4; ++mt)
      #pragma unroll
      for (int r = 0; r < 4; ++r) {
        int row = row0 + wm*64 + mt*16 + lkg*4 + r;
        #pragma unroll
        for (int nt = 0; nt < 4; ++nt) {
          int col = col0 + wn*64 + nt*16 + lr - 3072;
          bmraw[(size_t)row*128 + col] = acc[mt][nt][r];
        }
      }
  }
}

// ---------------- generic bf16 MFMA GEMM (Wout): C fp32 = A@W^T + bias + res ----------------
__global__ __launch_bounds__(256) void gemm_mfma_k(
    const u16* __restrict__ A, const u16* __restrict__ W,
    const float* __restrict__ bias, const float* __restrict__ res,
    float* __restrict__ Cf, int N, int K)
{
  __shared__ u16 As[128*64];
  __shared__ u16 Ws[128*64];
  const int tid = threadIdx.x;
  const int lane = tid & 63;
  const int wave = tid >> 6;
  const int wm = wave >> 1, wn = wave & 1;
  const int row0 = blockIdx.y*128, col0 = blockIdx.x*128;
  const int lr = lane & 15, lkg = lane >> 4;
  floatx4 acc[4][4];
  #pragma unroll
  for (int mt=0; mt<4; ++mt)
    #pragma unroll
    for (int nt=0; nt<4; ++nt)
      acc[mt][nt] = (floatx4){0.f,0.f,0.f,0.f};
  for (int k0 = 0; k0 < K; k0 += 64) {
    __syncthreads();
    #pragma unroll
    for (int it = 0; it < 4; ++it) {
      int li  = it*256 + tid;
      int row = li >> 3, ckp = li & 7;
      int ck  = ckp ^ (row & 7);
      const u16* ga = A + (size_t)(row0+row)*K + k0 + ck*8;
      const u16* gw = W + (size_t)(col0+row)*K + k0 + ck*8;
      __builtin_amdgcn_global_load_lds(
          (const __attribute__((address_space(1))) void*)ga,
          (__attribute__((address_space(3))) void*)(As + (size_t)(li & ~63)*8), 16, 0, 0);
      __builtin_amdgcn_global_load_lds(
          (const __attribute__((address_space(1))) void*)gw,
          (__attribute__((address_space(3))) void*)(Ws + (size_t)(li & ~63)*8), 16, 0, 0);
    }
    __syncthreads();
    #pragma unroll
    for (int kk = 0; kk < 64; kk += 32) {
      short8 af[4], wf[4];
      const int ckw = (kk >> 3) + lkg;
      #pragma unroll
      for (int t = 0; t < 4; ++t) {
        int rowA = wm*64 + t*16 + lr;
        int rowW = wn*64 + t*16 + lr;
        af[t] = *reinterpret_cast<const short8*>(As + rowA*64 + (ckw ^ (rowA & 7))*8);
        wf[t] = *reinterpret_cast<const short8*>(Ws + rowW*64 + (ckw ^ (rowW & 7))*8);
      }
      #pragma unroll
      for (int mt = 0; mt < 4; ++mt)
        #pragma unroll
        for (int nt = 0; nt < 4; ++nt)
          acc[mt][nt] = __builtin_amdgcn_mfma_f32_16x16x32_bf16(af[mt], wf[nt], acc[mt][nt], 0, 0, 0);
    }
  }
  #pragma unroll
  for (int mt = 0; mt < 4; ++mt) {
    #pragma unroll
    for (int r = 0; r < 4; ++r) {
      int row = row0 + wm*64 + mt*16 + lkg*4 + r;
      #pragma unroll
      for (int nt = 0; nt < 4; ++nt) {
        int col = col0 + wn*64 + nt*16 + lr;
        float v = acc[mt][nt][r];
        if (bias) v += bias[col];
        if (res)  v += res[(size_t)row*N + col];
        Cf[(size_t)row*N + col] = v;
      }
    }
  }
}

// ---------------- scan pass 1: per-chunk deltas via MFMA ----------------
// grid (ch,h,b), 256 thr, 4 waves: wave=(m,mt). dS[bh][ch][m][32][32], dK, pL, p.
__global__ __launch_bounds__(256) void scan_delta_k(
    const u16* __restrict__ qkv, const float* __restrict__ bmraw,
    const float* __restrict__ bbeta,
    float* __restrict__ dS, float* __restrict__ dK,
    float* __restrict__ pLg, float* __restrict__ pg)
{
  __shared__ __align__(16) u16 K2T[2][32][72];
  __shared__ __align__(16) u16 VT[32][72];
  __shared__ float bets[2][64], pbuf[2][64], wjs[2][64], pLs[2];
  const int ch = blockIdx.x, h = blockIdx.y, b = blockIdx.z;
  const int bh = b*NHH + h;
  const int tid = threadIdx.x;
  const int t0 = ch*CL;
  const int j = tid >> 2, oct = tid & 3;
  size_t rowbase = (size_t)(b*TT + t0 + j)*3072 + h*32 + oct*8;
  u16x8 k8 = *reinterpret_cast<const u16x8*>(qkv + rowbase + 1024);
  u16x8 v8 = *reinterpret_cast<const u16x8*>(qkv + rowbase + 2048);
  if (tid < 128) {
    int m = tid & 1, tl = tid >> 1;
    float bv = bmraw[(size_t)(b*TT + t0 + tl)*128 + h*2 + m] + bbeta[h*2 + m];
    bets[m][tl] = fminf(fmaxf(sigmoidf_(bv), 0.85f), 0.9995f);
  }
  #pragma unroll
  for (int dd = 0; dd < 8; ++dd) VT[oct*8+dd][j] = v8[dd];
  __syncthreads();
  if (tid < 128) {
    int m = tid >> 6, l = tid & 63;
    float p = bets[m][l];
    #pragma unroll
    for (int off = 1; off < 64; off <<= 1) {
      float o = __shfl_up(p, off);
      if (l >= off) p *= o;
    }
    pbuf[m][l] = p;
    if (l == 63) pLs[m] = p;
  }
  __syncthreads();
  if (tid < 128) {
    int m = tid >> 6, l = tid & 63;
    wjs[m][l] = pLs[m] / pbuf[m][l];
    pg[(((size_t)bh*NCH + ch)*2 + m)*64 + l] = pbuf[m][l];
  }
  if (tid < 2) pLg[((size_t)bh*NCH + ch)*2 + tid] = pLs[tid];
  __syncthreads();
  float w0 = wjs[0][j], w1 = wjs[1][j];
  #pragma unroll
  for (int dd = 0; dd < 8; ++dd) {
    float kv = b2f(k8[dd]);
    K2T[0][oct*8+dd][j] = f2b(kv*w0);
    K2T[1][oct*8+dd][j] = f2b(kv*w1);
  }
  __syncthreads();
  {
    const int wv = tid >> 6, lane = tid & 63, lr = lane & 15, kg = lane >> 4;
    const int m = wv >> 1, mt = wv & 1;
    floatx4 a0 = (floatx4){0.f,0.f,0.f,0.f}, a1 = (floatx4){0.f,0.f,0.f,0.f};
    #pragma unroll
    for (int ks = 0; ks < 2; ++ks) {
      short8 af = *reinterpret_cast<const short8*>(&K2T[m][mt*16 + lr][ks*32 + kg*8]);
      short8 b0 = *reinterpret_cast<const short8*>(&VT[lr][ks*32 + kg*8]);
      short8 b1 = *reinterpret_cast<const short8*>(&VT[16 + lr][ks*32 + kg*8]);
      a0 = __builtin_amdgcn_mfma_f32_16x16x32_bf16(af, b0, a0, 0, 0, 0);
      a1 = __builtin_amdgcn_mfma_f32_16x16x32_bf16(af, b1, a1, 0, 0, 0);
    }
    size_t base = (((size_t)bh*NCH + ch)*2 + m)*1024;
    #pragma unroll
    for (int r = 0; r < 4; ++r) {
      int d = mt*16 + kg*4 + r;
      dS[base + d*32 + lr]      = a0[r];
      dS[base + d*32 + 16 + lr] = a1[r];
    }
  }
  if (tid < 64) {
    int m = tid >> 5, d = tid & 31;
    float s = 0.f;
    #pragma unroll
    for (int g = 0; g < 8; ++g) {
      u16x8 kk = *reinterpret_cast<const u16x8*>(&K2T[m][d][g*8]);
      #pragma unroll
      for (int dd = 0; dd < 8; ++dd) s += b2f(kk[dd]);
    }
    dK[(((size_t)bh*NCH + ch)*2 + m)*32 + d] = s;
  }
}

// ---------------- scan pass 2: prefix scan across chunks (register-pipelined) ----------------
__global__ __launch_bounds__(1024) void scan_state_k(
    float* dSS0, float* dKK0, const float* __restrict__ pLg)
{
  const int bhm = blockIdx.x;   // 256 = bh*2+m
  const int bh = bhm >> 1, m = bhm & 1;
  const int tid = threadIdx.x;
  float pls[NCH], dv[NCH];
  #pragma unroll
  for (int ch = 0; ch < NCH; ++ch) pls[ch] = pLg[((size_t)bh*NCH + ch)*2 + m];
  #pragma unroll
  for (int ch = 0; ch < NCH; ++ch) dv[ch] = dSS0[(((size_t)bh*NCH + ch)*2 + m)*1024 + tid];
  float S = 0.f;
  #pragma unroll
  for (int ch = 0; ch < NCH; ++ch) {
    dSS0[(((size_t)bh*NCH + ch)*2 + m)*1024 + tid] = S;
    S = fmaf(pls[ch], S, dv[ch]);
  }
  if (tid < 32) {
    float kv[NCH];
    #pragma unroll
    for (int ch = 0; ch < NCH; ++ch) kv[ch] = dKK0[(((size_t)bh*NCH + ch)*2 + m)*32 + tid];
    float K0 = 0.f;
    #pragma unroll
    for (int ch = 0; ch < NCH; ++ch) {
      dKK0[(((size_t)bh*NCH + ch)*2 + m)*32 + tid] = K0;
      K0 = fmaf(pls[ch], K0, kv[ch]);
    }
  }
}

// ---------------- scan pass 3: A0=QK^T, Atilde, den, y via MFMA ----------------
__global__ __launch_bounds__(256) void scan_apply_k(
    const u16* __restrict__ qkv, const float* __restrict__ bmraw,
    const float* __restrict__ bmix,
    const float* __restrict__ S0g, const float* __restrict__ K0g,
    const float* __restrict__ pg, u16* __restrict__ yb)
{
  __shared__ __align__(16) u16 Qs[64][32], Ks[64][32];
  __shared__ __align__(16) u16 VT[32][72];
  __shared__ __align__(16) u16 At[2][64][72];
  __shared__ __align__(16) u16 S0T[2][2][32][40];   // [m][hi/lo][c][d]
  __shared__ float K0s[2][32];
  __shared__ float pbv[2][64], ipb[2][64], mixs[2][64], coef[2][64];
  const int ch = blockIdx.x, h = blockIdx.y, b = blockIdx.z;
  const int bh = b*NHH + h;
  const int tid = threadIdx.x;
  const int t0 = ch*CL;
  {
    int j = tid >> 2, oct = tid & 3;
    size_t rb = (size_t)(b*TT + t0 + j)*3072 + h*32 + oct*8;
    u16x8 q8 = *reinterpret_cast<const u16x8*>(qkv + rb);
    u16x8 k8 = *reinterpret_cast<const u16x8*>(qkv + rb + 1024);
    u16x8 v8 = *reinterpret_cast<const u16x8*>(qkv + rb + 2048);
    *reinterpret_cast<u16x8*>(&Qs[j][oct*8]) = q8;
    *reinterpret_cast<u16x8*>(&Ks[j][oct*8]) = k8;
    #pragma unroll
    for (int dd = 0; dd < 8; ++dd) VT[oct*8+dd][j] = v8[dd];
  }
  for (int u = tid; u < 2048; u += 256) {
    int m = u >> 10, r = u & 1023, d = r >> 5, c = r & 31;
    float val = S0g[(((size_t)bh*NCH + ch)*2 + m)*1024 + r];
    u16 hv = f2b(val);
    float lo = val - b2f(hv);
    S0T[m][0][c][d] = hv;
    S0T[m][1][c][d] = f2b(lo);
  }
  if (tid < 64) {
    int m = tid >> 5, d = tid & 31;
    K0s[m][d] = K0g[(((size_t)bh*NCH + ch)*2 + m)*32 + d];
  }
  if (tid < 128) {
    int m = tid & 1, i = tid >> 1;
    float p = pg[(((size_t)bh*NCH + ch)*2 + m)*64 + i];
    pbv[m][i] = p;
    ipb[m][i] = 1.f/p;
  } else if (tid < 192) {
    int i = tid - 128;
    size_t rb = (size_t)(b*TT + t0 + i)*128 + 64 + h*2;
    float a0 = bmraw[rb]   + bmix[h*2];
    float a1 = bmraw[rb+1] + bmix[h*2+1];
    float mx = fmaxf(a0, a1);
    float e0 = expf(a0-mx), e1 = expf(a1-mx);
    float inv = 1.f/(e0+e1);
    mixs[0][i] = e0*inv; mixs[1][i] = e1*inv;
  }
  __syncthreads();
  // A0 = Q K^T (wave wv owns row-tile wv), masked+scaled into At (bf16)
  {
    const int wv = tid >> 6, lane = tid & 63, lr = lane & 15, kg = lane >> 4;
    short8 aq = *reinterpret_cast<const short8*>(&Qs[wv*16 + lr][kg*8]);
    #pragma unroll
    for (int nt = 0; nt < 4; ++nt) {
      short8 bk = *reinterpret_cast<const short8*>(&Ks[nt*16 + lr][kg*8]);
      floatx4 a0 = (floatx4){0.f,0.f,0.f,0.f};
      a0 = __builtin_amdgcn_mfma_f32_16x16x32_bf16(aq, bk, a0, 0, 0, 0);
      int jg = nt*16 + lr;
      float ip0 = ipb[0][jg], ip1 = ipb[1][jg];
      #pragma unroll
      for (int r = 0; r < 4; ++r) {
        int ig = wv*16 + kg*4 + r;
        float val = a0[r];
        bool ok = (jg <= ig);
        At[0][ig][jg] = f2b(ok ? val*ip0 : 0.f);
        At[1][ig][jg] = f2b(ok ? val*ip1 : 0.f);
      }
    }
  }
  __syncthreads();
  // den + coef
  if (tid < 128) {
    int m = tid & 1, i = tid >> 1;
    float qK0 = 0.f;
    #pragma unroll
    for (int g = 0; g < 4; ++g) {
      u16x8 qq = *reinterpret_cast<const u16x8*>(&Qs[i][g*8]);
      #pragma unroll
      for (int dd = 0; dd < 8; ++dd) qK0 = fmaf(b2f(qq[dd]), K0s[m][g*8+dd], qK0);
    }
    float As_ = 0.f;
    #pragma unroll
    for (int g = 0; g < 8; ++g) {
      u16x8 aa = *reinterpret_cast<const u16x8*>(&At[m][i][g*8]);
      #pragma unroll
      for (int dd = 0; dd < 8; ++dd) As_ += b2f(aa[dd]);
    }
    float den = pbv[m][i]*(qK0 + As_) + 1e-6f;
    coef[m][i] = mixs[m][i]*pbv[m][i]/den;
  }
  __syncthreads();
  // y = coef0*(Q S0_0 + At0 V) + coef1*(Q S0_1 + At1 V)
  {
    const int wv = tid >> 6, lane = tid & 63, lr = lane & 15, kg = lane >> 4;
    const int i0 = wv*16;
    floatx4 accY[2][2];
    #pragma unroll
    for (int m = 0; m < 2; ++m)
      #pragma unroll
      for (int nt = 0; nt < 2; ++nt)
        accY[m][nt] = (floatx4){0.f,0.f,0.f,0.f};
    short8 aq = *reinterpret_cast<const short8*>(&Qs[i0 + lr][kg*8]);
    #pragma unroll
    for (int m = 0; m < 2; ++m)
      #pragma unroll
      for (int nt = 0; nt < 2; ++nt) {
        short8 bhi = *reinterpret_cast<const short8*>(&S0T[m][0][nt*16 + lr][kg*8]);
        short8 blo = *reinterpret_cast<const short8*>(&S0T[m][1][nt*16 + lr][kg*8]);
        accY[m][nt] = __builtin_amdgcn_mfma_f32_16x16x32_bf16(aq, bhi, accY[m][nt], 0, 0, 0);
        accY[m][nt] = __builtin_amdgcn_mfma_f32_16x16x32_bf16(aq, blo, accY[m][nt], 0, 0, 0);
      }
    #pragma unroll
    for (int ks = 0; ks < 2; ++ks) {
      short8 a0f = *reinterpret_cast<const short8*>(&At[0][i0 + lr][ks*32 + kg*8]);
      short8 a1f = *reinterpret_cast<const short8*>(&At[1][i0 + lr][ks*32 + kg*8]);
      short8 b0 = *reinterpret_cast<const short8*>(&VT[lr][ks*32 + kg*8]);
      short8 b1 = *reinterpret_cast<const short8*>(&VT[16 + lr][ks*32 + kg*8]);
      accY[0][0] = __builtin_amdgcn_mfma_f32_16x16x32_bf16(a0f, b0, accY[0][0], 0, 0, 0);
      accY[0][1] = __builtin_amdgcn_mfma_f32_16x16x32_bf16(a0f, b1, accY[0][1], 0, 0, 0);
      accY[1][0] = __builtin_amdgcn_mfma_f32_16x16x32_bf16(a1f, b0, accY[1][0], 0, 0, 0);
      accY[1][1] = __builtin_amdgcn_mfma_f32_16x16x32_bf16(a1f, b1, accY[1][1], 0, 0, 0);
    }
    #pragma unroll
    for (int r = 0; r < 4; ++r) {
      int i = i0 + kg*4 + r;
      float c0 = coef[0][i], c1 = coef[1][i];
      size_t ob = (size_t)(b*TT + t0 + i)*HH + h*32;
      yb[ob + lr]      = f2b(c0*accY[0][0][r] + c1*accY[1][0][r]);
      yb[ob + 16 + lr] = f2b(c0*accY[0][1][r] + c1*accY[1][1][r]);
    }
  }
}

// ---------------- LayerNorm ----------------
__global__ __launch_bounds__(256) void ln_k(
    const float* __restrict__ z, const float* __restrict__ g,
    const float* __restrict__ bta, float* __restrict__ out)
{
  const int row = blockIdx.x;
  const int tid = threadIdx.x;
  const float* zr = z + (size_t)row*HH;
  float4 zv = reinterpret_cast<const float4*>(zr)[tid];
  float sum = zv.x+zv.y+zv.z+zv.w;
  float sq  = zv.x*zv.x + zv.y*zv.y + zv.z*zv.z + zv.w*zv.w;
  #pragma unroll
  for (int off=1; off<64; off<<=1){ sum += __shfl_xor(sum, off); sq += __shfl_xor(sq, off); }
  __shared__ float s1[4], s2[4];
  int w = tid>>6;
  if ((tid&63)==0){ s1[w]=sum; s2[w]=sq; }
  __syncthreads();
  sum = s1[0]+s1[1]+s1[2]+s1[3];
  sq  = s2[0]+s2[1]+s2[2]+s2[3];
  float mu  = sum * (1.f/1024.f);
  float var = sq * (1.f/1024.f) - mu*mu;
  float rstd = rsqrtf(var + 1e-5f);
  float4 gv = reinterpret_cast<const float4*>(g)[tid];
  float4 bv = reinterpret_cast<const float4*>(bta)[tid];
  float4 ov;
  ov.x = (zv.x-mu)*rstd*gv.x + bv.x;
  ov.y = (zv.y-mu)*rstd*gv.y + bv.y;
  ov.z = (zv.z-mu)*rstd*gv.z + bv.z;
  ov.w = (zv.w-mu)*rstd*gv.w + bv.w;
  reinterpret_cast<float4*>(out + (size_t)row*HH)[tid] = ov;
}

extern "C" void kernel_launch(void* const* d_in, const int* in_sizes, int n_in,
                              void* d_out, int out_size, void* d_ws, size_t ws_size,
                              hipStream_t stream)
{
  const float* x     = (const float*)d_in[0];
  const float* Wq    = (const float*)d_in[1];
  const float* Wk    = (const float*)d_in[2];
  const float* Wv    = (const float*)d_in[3];
  const float* Wbeta = (const float*)d_in[4];
  const float* bbeta = (const float*)d_in[5];
  const float* Wmix  = (const float*)d_in[6];
  const float* bmix  = (const float*)d_in[7];
  const float* Wout  = (const float*)d_in[8];
  const float* bout  = (const float*)d_in[9];
  const float* ln_g  = (const float*)d_in[10];
  const float* ln_b  = (const float*)d_in[11];
  float* out = (float*)d_out;

  float* ws = (float*)d_ws;
  float* ct      = ws;                       // 16384
  float* st      = ws + 16384;               // 16384
  u16*   x_bf    = (u16*)(ws + 32768);       // 4194304 u16 (reused as y_bf)
  u16*   Wf      = (u16*)(ws + 2129920);     // 3276800 u16 [Wq|Wk|Wv|Wbeta|Wmix]
  u16*   Wout_bf = (u16*)(ws + 3768320);     // 1048576 u16
  u16*   qkv     = (u16*)(ws + 4292608);     // 12582912 u16
  float* bmraw   = ws + 10584064;            // 524288
  float* dSS0    = ws + 11108352;            // 4194304 (reused as z)
  float* dKK0    = ws + 15302656;            // 131072
  float* pLg     = ws + 15433728;            // 4096
  float* pg      = ws + 15437824;            // 262144
  u16*   y_bf    = x_bf;
  float* z       = dSS0;

  cast_all_k<<<8320, 256, 0, stream>>>(x, Wq, Wk, Wv, Wbeta, Wmix, Wout, x_bf, Wf, Wout_bf);
  rope_table_k<<<64, 256, 0, stream>>>(ct, st);
  gemm_qkv_k<<<dim3(25, 32), 256, 0, stream>>>(x_bf, Wf, ct, st, qkv, bmraw);
  dim3 gscan(NCH, 32, 4);
  scan_delta_k<<<gscan, 256, 0, stream>>>(qkv, bmraw, bbeta, dSS0, dKK0, pLg, pg);
  scan_state_k<<<256, 1024, 0, stream>>>(dSS0, dKK0, pLg);
  scan_apply_k<<<gscan, 256, 0, stream>>>(qkv, bmraw, bmix, dSS0, dKK0, pg, y_bf);
  gemm_mfma_k<<<dim3(8, 32), 256, 0, stream>>>(y_bf, Wout_bf, bout, x, z, 1024, 1024);
  ln_k<<<4096, 256, 0, stream>>>(z, ln_g, ln_b, out);
}

// Round 5
// 224.374 us; speedup vs baseline: 7.0974x; 1.0604x over previous
//
#include <hip/hip_runtime.h>
#include <math.h>

#define TT 1024
#define BB 4
#define HH 1024
#define NHH 32
#define CL 64
#define NCH (TT/CL)

typedef unsigned short u16;
typedef __attribute__((ext_vector_type(8))) short short8;
typedef __attribute__((ext_vector_type(8))) unsigned short u16x8;
typedef __attribute__((ext_vector_type(4))) float floatx4;

__device__ __forceinline__ float sigmoidf_(float x){ return 1.f/(1.f+expf(-x)); }
__device__ __forceinline__ u16 f2b(float f){
  union { float f; unsigned u; } x; x.f = f;
  unsigned r = x.u + 0x7FFFu + ((x.u >> 16) & 1u);
  return (u16)(r >> 16);
}
__device__ __forceinline__ float b2f(u16 v){
  union { unsigned u; float f; } x; x.u = ((unsigned)v) << 16;
  return x.f;
}

// ---------------- cast fp32 -> bf16 (x, [Wq|Wk|Wv|Wbeta|Wmix], Wout) + rope table ----------------
__global__ __launch_bounds__(256) void cast_all_k(
    const float* __restrict__ x, const float* __restrict__ Wq, const float* __restrict__ Wk,
    const float* __restrict__ Wv, const float* __restrict__ Wbeta, const float* __restrict__ Wmix,
    const float* __restrict__ Wout,
    u16* __restrict__ x_bf, u16* __restrict__ Wf, u16* __restrict__ Wout_bf,
    float* __restrict__ ct, float* __restrict__ st)
{
  int gid = blockIdx.x*256 + threadIdx.x;
  if (gid < 16384) {   // rope table: t=gid>>4, j=gid&15
    int t = gid >> 4, j = gid & 15;
    float invf = powf(10000.f, -(float)j/16.f);
    float ang = (float)t * invf;
    ct[gid] = cosf(ang);
    st[gid] = sinf(ang);
  }
  size_t e = (size_t)gid*4;   // 8519680 total elems
  const float* src; u16* dst; size_t so, dof;
  if      (e < 4194304) { src=x;     dst=x_bf;    so=e;          dof=so; }
  else if (e < 5242880) { src=Wq;    dst=Wf;      so=e-4194304;  dof=so; }
  else if (e < 6291456) { src=Wk;    dst=Wf;      so=e-5242880;  dof=so+1048576; }
  else if (e < 7340032) { src=Wv;    dst=Wf;      so=e-6291456;  dof=so+2097152; }
  else if (e < 7405568) { src=Wbeta; dst=Wf;      so=e-7340032;  dof=so+3145728; }
  else if (e < 7471104) { src=Wmix;  dst=Wf;      so=e-7405568;  dof=so+3211264; }
  else                  { src=Wout;  dst=Wout_bf; so=e-7471104;  dof=so; }
  float4 f = *reinterpret_cast<const float4*>(src + so);
  ushort4 u; u.x=f2b(f.x); u.y=f2b(f.y); u.z=f2b(f.z); u.w=f2b(f.w);
  *reinterpret_cast<ushort4*>(dst + dof) = u;
}

// ---------------- fused QKV+beta/mix GEMM, N=3200, rope/elu/sigmoid/softmax epilogue ----------
// 1-D grid 800, row-fastest: by=id&31, bx=id>>5 (32%8==0 keeps per-XCD A-tiles fixed).
__global__ __launch_bounds__(256) void gemm_qkv_k(
    const u16* __restrict__ A, const u16* __restrict__ W,
    const float* __restrict__ ct, const float* __restrict__ st,
    const float* __restrict__ bbeta, const float* __restrict__ bmix,
    u16* __restrict__ qkv, float* __restrict__ betag, float* __restrict__ mixg)
{
  __shared__ u16 As[128*64];
  __shared__ u16 Ws[128*64];
  const int tid = threadIdx.x;
  const int lane = tid & 63;
  const int wave = tid >> 6;
  const int wm = wave >> 1, wn = wave & 1;
  const int id = blockIdx.x;
  const int row0 = (id & 31)*128, bx = id >> 5, col0 = bx*128;
  const int lr = lane & 15, lkg = lane >> 4;

  floatx4 acc[4][4];
  #pragma unroll
  for (int mt=0; mt<4; ++mt)
    #pragma unroll
    for (int nt=0; nt<4; ++nt)
      acc[mt][nt] = (floatx4){0.f,0.f,0.f,0.f};

  for (int k0 = 0; k0 < 1024; k0 += 64) {
    __syncthreads();
    #pragma unroll
    for (int it = 0; it < 4; ++it) {
      int li  = it*256 + tid;
      int row = li >> 3, ckp = li & 7;
      int ck  = ckp ^ (row & 7);
      const u16* ga = A + (size_t)(row0+row)*1024 + k0 + ck*8;
      const u16* gw = W + (size_t)(col0+row)*1024 + k0 + ck*8;
      __builtin_amdgcn_global_load_lds(
          (const __attribute__((address_space(1))) void*)ga,
          (__attribute__((address_space(3))) void*)(As + (size_t)(li & ~63)*8), 16, 0, 0);
      __builtin_amdgcn_global_load_lds(
          (const __attribute__((address_space(1))) void*)gw,
          (__attribute__((address_space(3))) void*)(Ws + (size_t)(li & ~63)*8), 16, 0, 0);
    }
    __syncthreads();
    #pragma unroll
    for (int kk = 0; kk < 64; kk += 32) {
      short8 af[4], wf[4];
      const int ckw = (kk >> 3) + lkg;
      #pragma unroll
      for (int t = 0; t < 4; ++t) {
        int rowA = wm*64 + t*16 + lr;
        int rowW = wn*64 + t*16 + lr;
        af[t] = *reinterpret_cast<const short8*>(As + rowA*64 + (ckw ^ (rowA & 7))*8);
        wf[t] = *reinterpret_cast<const short8*>(Ws + rowW*64 + (ckw ^ (rowW & 7))*8);
      }
      #pragma unroll
      for (int mt = 0; mt < 4; ++mt)
        #pragma unroll
        for (int nt = 0; nt < 4; ++nt)
          acc[mt][nt] = __builtin_amdgcn_mfma_f32_16x16x32_bf16(af[mt], wf[nt], acc[mt][nt], 0, 0, 0);
    }
  }
  if (bx < 16) {
    // q/k region: rope + elu+1
    #pragma unroll
    for (int mt = 0; mt < 4; ++mt) {
      #pragma unroll
      for (int r = 0; r < 4; ++r) {
        int row = row0 + wm*64 + mt*16 + lkg*4 + r;
        int t = row & (TT-1);
        float c_ = ct[t*16 + lr], s_ = st[t*16 + lr];
        #pragma unroll
        for (int nt = 0; nt < 4; nt += 2) {
          float u1 = acc[mt][nt][r], u2 = acc[mt][nt+1][r];
          float r1 = u1*c_ - u2*s_;
          float r2 = u1*s_ + u2*c_;
          r1 = r1 > 0.f ? r1+1.f : expf(r1);
          r2 = r2 > 0.f ? r2+1.f : expf(r2);
          int col = col0 + wn*64 + nt*16 + lr;
          qkv[(size_t)row*3072 + col]      = f2b(r1);
          qkv[(size_t)row*3072 + col + 16] = f2b(r2);
        }
      }
    }
  } else if (bx < 24) {
    // v region: passthrough bf16
    #pragma unroll
    for (int mt = 0; mt < 4; ++mt)
      #pragma unroll
      for (int r = 0; r < 4; ++r) {
        int row = row0 + wm*64 + mt*16 + lkg*4 + r;
        #pragma unroll
        for (int nt = 0; nt < 4; ++nt) {
          int col = col0 + wn*64 + nt*16 + lr;
          qkv[(size_t)row*3072 + col] = f2b(acc[mt][nt][r]);
        }
      }
  } else {
    // beta (wn=0) / mix (wn=1) regions, cols 3072..3199. cidx = nt*16+lr in 0..63 = h*2+m.
    #pragma unroll
    for (int mt = 0; mt < 4; ++mt)
      #pragma unroll
      for (int r = 0; r < 4; ++r) {
        int row = row0 + wm*64 + mt*16 + lkg*4 + r;
        #pragma unroll
        for (int nt = 0; nt < 4; ++nt) {
          int cidx = nt*16 + lr;
          float v = acc[mt][nt][r];
          if (wn == 0) {
            float bv = sigmoidf_(v + bbeta[cidx]);
            betag[(size_t)row*64 + cidx] = fminf(fmaxf(bv, 0.85f), 0.9995f);
          } else {
            float a = v + bmix[cidx];
            float o = __shfl_xor(a, 1);
            float e = expf(a - fmaxf(a, o));
            float es = e + __shfl_xor(e, 1);
            mixg[(size_t)row*64 + cidx] = e/es;
          }
        }
      }
  }
}

// ---------------- out-projection, split-K=2: Zp[kh] = y @ Wout^T (K-half) ----------------
// 1-D grid 512: by=id&31, bx=(id>>5)&7, kh=id>>8.
__global__ __launch_bounds__(256) void gemm_out_k(
    const u16* __restrict__ A, const u16* __restrict__ W,
    float* __restrict__ Zp0, float* __restrict__ Zp1)
{
  __shared__ u16 As[128*64];
  __shared__ u16 Ws[128*64];
  const int tid = threadIdx.x;
  const int lane = tid & 63;
  const int wave = tid >> 6;
  const int wm = wave >> 1, wn = wave & 1;
  const int id = blockIdx.x;
  const int row0 = (id & 31)*128, col0 = ((id >> 5) & 7)*128, kh = id >> 8;
  float* Z = kh ? Zp1 : Zp0;
  const int lr = lane & 15, lkg = lane >> 4;
  floatx4 acc[4][4];
  #pragma unroll
  for (int mt=0; mt<4; ++mt)
    #pragma unroll
    for (int nt=0; nt<4; ++nt)
      acc[mt][nt] = (floatx4){0.f,0.f,0.f,0.f};
  for (int k0 = kh*512; k0 < kh*512 + 512; k0 += 64) {
    __syncthreads();
    #pragma unroll
    for (int it = 0; it < 4; ++it) {
      int li  = it*256 + tid;
      int row = li >> 3, ckp = li & 7;
      int ck  = ckp ^ (row & 7);
      const u16* ga = A + (size_t)(row0+row)*1024 + k0 + ck*8;
      const u16* gw = W + (size_t)(col0+row)*1024 + k0 + ck*8;
      __builtin_amdgcn_global_load_lds(
          (const __attribute__((address_space(1))) void*)ga,
          (__attribute__((address_space(3))) void*)(As + (size_t)(li & ~63)*8), 16, 0, 0);
      __builtin_amdgcn_global_load_lds(
          (const __attribute__((address_space(1))) void*)gw,
          (__attribute__((address_space(3))) void*)(Ws + (size_t)(li & ~63)*8), 16, 0, 0);
    }
    __syncthreads();
    #pragma unroll
    for (int kk = 0; kk < 64; kk += 32) {
      short8 af[4], wf[4];
      const int ckw = (kk >> 3) + lkg;
      #pragma unroll
      for (int t = 0; t < 4; ++t) {
        int rowA = wm*64 + t*16 + lr;
        int rowW = wn*64 + t*16 + lr;
        af[t] = *reinterpret_cast<const short8*>(As + rowA*64 + (ckw ^ (rowA & 7))*8);
        wf[t] = *reinterpret_cast<const short8*>(Ws + rowW*64 + (ckw ^ (rowW & 7))*8);
      }
      #pragma unroll
      for (int mt = 0; mt < 4; ++mt)
        #pragma unroll
        for (int nt = 0; nt < 4; ++nt)
          acc[mt][nt] = __builtin_amdgcn_mfma_f32_16x16x32_bf16(af[mt], wf[nt], acc[mt][nt], 0, 0, 0);
    }
  }
  #pragma unroll
  for (int mt = 0; mt < 4; ++mt)
    #pragma unroll
    for (int r = 0; r < 4; ++r) {
      int row = row0 + wm*64 + mt*16 + lkg*4 + r;
      #pragma unroll
      for (int nt = 0; nt < 4; ++nt) {
        int col = col0 + wn*64 + nt*16 + lr;
        Z[(size_t)row*HH + col] = acc[mt][nt][r];
      }
    }
}

// ---------------- scan pass 1: per-chunk deltas via MFMA ----------------
__global__ __launch_bounds__(256) void scan_delta_k(
    const u16* __restrict__ qkv, const float* __restrict__ betag,
    float* __restrict__ dS, float* __restrict__ dK,
    float* __restrict__ pLg, float* __restrict__ pg)
{
  __shared__ __align__(16) u16 K2T[2][32][72];
  __shared__ __align__(16) u16 VT[32][72];
  __shared__ float bets[2][64], pbuf[2][64], wjs[2][64], pLs[2];
  const int ch = blockIdx.x, h = blockIdx.y, b = blockIdx.z;
  const int bh = b*NHH + h;
  const int tid = threadIdx.x;
  const int t0 = ch*CL;
  const int j = tid >> 2, oct = tid & 3;
  size_t rowbase = (size_t)(b*TT + t0 + j)*3072 + h*32 + oct*8;
  u16x8 k8 = *reinterpret_cast<const u16x8*>(qkv + rowbase + 1024);
  u16x8 v8 = *reinterpret_cast<const u16x8*>(qkv + rowbase + 2048);
  if (tid < 128) {
    int m = tid & 1, tl = tid >> 1;
    bets[m][tl] = betag[(size_t)(b*TT + t0 + tl)*64 + h*2 + m];
  }
  #pragma unroll
  for (int dd = 0; dd < 8; ++dd) VT[oct*8+dd][j] = v8[dd];
  __syncthreads();
  if (tid < 128) {
    int m = tid >> 6, l = tid & 63;
    float p = bets[m][l];
    #pragma unroll
    for (int off = 1; off < 64; off <<= 1) {
      float o = __shfl_up(p, off);
      if (l >= off) p *= o;
    }
    pbuf[m][l] = p;
    if (l == 63) pLs[m] = p;
  }
  __syncthreads();
  if (tid < 128) {
    int m = tid >> 6, l = tid & 63;
    wjs[m][l] = pLs[m] / pbuf[m][l];
    pg[(((size_t)bh*NCH + ch)*2 + m)*64 + l] = pbuf[m][l];
  }
  if (tid < 2) pLg[((size_t)bh*NCH + ch)*2 + tid] = pLs[tid];
  __syncthreads();
  float w0 = wjs[0][j], w1 = wjs[1][j];
  #pragma unroll
  for (int dd = 0; dd < 8; ++dd) {
    float kv = b2f(k8[dd]);
    K2T[0][oct*8+dd][j] = f2b(kv*w0);
    K2T[1][oct*8+dd][j] = f2b(kv*w1);
  }
  __syncthreads();
  {
    const int wv = tid >> 6, lane = tid & 63, lr = lane & 15, kg = lane >> 4;
    const int m = wv >> 1, mt = wv & 1;
    floatx4 a0 = (floatx4){0.f,0.f,0.f,0.f}, a1 = (floatx4){0.f,0.f,0.f,0.f};
    #pragma unroll
    for (int ks = 0; ks < 2; ++ks) {
      short8 af = *reinterpret_cast<const short8*>(&K2T[m][mt*16 + lr][ks*32 + kg*8]);
      short8 b0 = *reinterpret_cast<const short8*>(&VT[lr][ks*32 + kg*8]);
      short8 b1 = *reinterpret_cast<const short8*>(&VT[16 + lr][ks*32 + kg*8]);
      a0 = __builtin_amdgcn_mfma_f32_16x16x32_bf16(af, b0, a0, 0, 0, 0);
      a1 = __builtin_amdgcn_mfma_f32_16x16x32_bf16(af, b1, a1, 0, 0, 0);
    }
    size_t base = (((size_t)bh*NCH + ch)*2 + m)*1024;
    #pragma unroll
    for (int r = 0; r < 4; ++r) {
      int d = mt*16 + kg*4 + r;
      dS[base + d*32 + lr]      = a0[r];
      dS[base + d*32 + 16 + lr] = a1[r];
    }
  }
  if (tid < 64) {
    int m = tid >> 5, d = tid & 31;
    float s = 0.f;
    #pragma unroll
    for (int g = 0; g < 8; ++g) {
      u16x8 kk = *reinterpret_cast<const u16x8*>(&K2T[m][d][g*8]);
      #pragma unroll
      for (int dd = 0; dd < 8; ++dd) s += b2f(kk[dd]);
    }
    dK[(((size_t)bh*NCH + ch)*2 + m)*32 + d] = s;
  }
}

// ---------------- scan pass 2: prefix scan across chunks ----------------
// grid 1024 = (bhm, part): part covers tid range part*256..+255 of the 1024 state elems.
__global__ __launch_bounds__(256) void scan_state_k(
    float* dSS0, float* dKK0, const float* __restrict__ pLg)
{
  const int bhm = blockIdx.x >> 2, part = blockIdx.x & 3;
  const int bh = bhm >> 1, m = bhm & 1;
  const int idx = part*256 + threadIdx.x;
  float pls[NCH], dv[NCH];
  #pragma unroll
  for (int ch = 0; ch < NCH; ++ch) pls[ch] = pLg[((size_t)bh*NCH + ch)*2 + m];
  #pragma unroll
  for (int ch = 0; ch < NCH; ++ch) dv[ch] = dSS0[(((size_t)bh*NCH + ch)*2 + m)*1024 + idx];
  float S = 0.f;
  #pragma unroll
  for (int ch = 0; ch < NCH; ++ch) {
    dSS0[(((size_t)bh*NCH + ch)*2 + m)*1024 + idx] = S;
    S = fmaf(pls[ch], S, dv[ch]);
  }
  if (part == 0 && threadIdx.x < 32) {
    int d = threadIdx.x;
    float kv[NCH];
    #pragma unroll
    for (int ch = 0; ch < NCH; ++ch) kv[ch] = dKK0[(((size_t)bh*NCH + ch)*2 + m)*32 + d];
    float K0 = 0.f;
    #pragma unroll
    for (int ch = 0; ch < NCH; ++ch) {
      dKK0[(((size_t)bh*NCH + ch)*2 + m)*32 + d] = K0;
      K0 = fmaf(pls[ch], K0, kv[ch]);
    }
  }
}

// ---------------- scan pass 3: A0=QK^T, Atilde, den, y via MFMA ----------------
__global__ __launch_bounds__(256) void scan_apply_k(
    const u16* __restrict__ qkv, const float* __restrict__ mixg,
    const float* __restrict__ S0g, const float* __restrict__ K0g,
    const float* __restrict__ pg, u16* __restrict__ yb)
{
  __shared__ __align__(16) u16 Qs[64][32], Ks[64][32];
  __shared__ __align__(16) u16 VT[32][72];
  __shared__ __align__(16) u16 At[2][64][72];
  __shared__ __align__(16) u16 S0T[2][2][32][40];
  __shared__ float K0s[2][32];
  __shared__ float pbv[2][64], ipb[2][64], mixs[2][64], coef[2][64];
  const int ch = blockIdx.x, h = blockIdx.y, b = blockIdx.z;
  const int bh = b*NHH + h;
  const int tid = threadIdx.x;
  const int t0 = ch*CL;
  {
    int j = tid >> 2, oct = tid & 3;
    size_t rb = (size_t)(b*TT + t0 + j)*3072 + h*32 + oct*8;
    u16x8 q8 = *reinterpret_cast<const u16x8*>(qkv + rb);
    u16x8 k8 = *reinterpret_cast<const u16x8*>(qkv + rb + 1024);
    u16x8 v8 = *reinterpret_cast<const u16x8*>(qkv + rb + 2048);
    *reinterpret_cast<u16x8*>(&Qs[j][oct*8]) = q8;
    *reinterpret_cast<u16x8*>(&Ks[j][oct*8]) = k8;
    #pragma unroll
    for (int dd = 0; dd < 8; ++dd) VT[oct*8+dd][j] = v8[dd];
  }
  for (int u = tid; u < 2048; u += 256) {
    int m = u >> 10, r = u & 1023, d = r >> 5, c = r & 31;
    float val = S0g[(((size_t)bh*NCH + ch)*2 + m)*1024 + r];
    u16 hv = f2b(val);
    float lo = val - b2f(hv);
    S0T[m][0][c][d] = hv;
    S0T[m][1][c][d] = f2b(lo);
  }
  if (tid < 64) {
    int m = tid >> 5, d = tid & 31;
    K0s[m][d] = K0g[(((size_t)bh*NCH + ch)*2 + m)*32 + d];
  }
  if (tid < 128) {
    int m = tid & 1, i = tid >> 1;
    float p = pg[(((size_t)bh*NCH + ch)*2 + m)*64 + i];
    pbv[m][i] = p;
    ipb[m][i] = 1.f/p;
  } else if (tid < 192) {
    int i = tid - 128;
    size_t rb = (size_t)(b*TT + t0 + i)*64 + h*2;
    mixs[0][i] = mixg[rb];
    mixs[1][i] = mixg[rb+1];
  }
  __syncthreads();
  {
    const int wv = tid >> 6, lane = tid & 63, lr = lane & 15, kg = lane >> 4;
    short8 aq = *reinterpret_cast<const short8*>(&Qs[wv*16 + lr][kg*8]);
    #pragma unroll
    for (int nt = 0; nt < 4; ++nt) {
      short8 bk = *reinterpret_cast<const short8*>(&Ks[nt*16 + lr][kg*8]);
      floatx4 a0 = (floatx4){0.f,0.f,0.f,0.f};
      a0 = __builtin_amdgcn_mfma_f32_16x16x32_bf16(aq, bk, a0, 0, 0, 0);
      int jg = nt*16 + lr;
      float ip0 = ipb[0][jg], ip1 = ipb[1][jg];
      #pragma unroll
      for (int r = 0; r < 4; ++r) {
        int ig = wv*16 + kg*4 + r;
        float val = a0[r];
        bool ok = (jg <= ig);
        At[0][ig][jg] = f2b(ok ? val*ip0 : 0.f);
        At[1][ig][jg] = f2b(ok ? val*ip1 : 0.f);
      }
    }
  }
  __syncthreads();
  if (tid < 128) {
    int m = tid & 1, i = tid >> 1;
    float qK0 = 0.f;
    #pragma unroll
    for (int g = 0; g < 4; ++g) {
      u16x8 qq = *reinterpret_cast<const u16x8*>(&Qs[i][g*8]);
      #pragma unroll
      for (int dd = 0; dd < 8; ++dd) qK0 = fmaf(b2f(qq[dd]), K0s[m][g*8+dd], qK0);
    }
    float As_ = 0.f;
    #pragma unroll
    for (int g = 0; g < 8; ++g) {
      u16x8 aa = *reinterpret_cast<const u16x8*>(&At[m][i][g*8]);
      #pragma unroll
      for (int dd = 0; dd < 8; ++dd) As_ += b2f(aa[dd]);
    }
    float den = pbv[m][i]*(qK0 + As_) + 1e-6f;
    coef[m][i] = mixs[m][i]*pbv[m][i]/den;
  }
  __syncthreads();
  {
    const int wv = tid >> 6, lane = tid & 63, lr = lane & 15, kg = lane >> 4;
    const int i0 = wv*16;
    floatx4 accY[2][2];
    #pragma unroll
    for (int m = 0; m < 2; ++m)
      #pragma unroll
      for (int nt = 0; nt < 2; ++nt)
        accY[m][nt] = (floatx4){0.f,0.f,0.f,0.f};
    short8 aq = *reinterpret_cast<const short8*>(&Qs[i0 + lr][kg*8]);
    #pragma unroll
    for (int m = 0; m < 2; ++m)
      #pragma unroll
      for (int nt = 0; nt < 2; ++nt) {
        short8 bhi = *reinterpret_cast<const short8*>(&S0T[m][0][nt*16 + lr][kg*8]);
        short8 blo = *reinterpret_cast<const short8*>(&S0T[m][1][nt*16 + lr][kg*8]);
        accY[m][nt] = __builtin_amdgcn_mfma_f32_16x16x32_bf16(aq, bhi, accY[m][nt], 0, 0, 0);
        accY[m][nt] = __builtin_amdgcn_mfma_f32_16x16x32_bf16(aq, blo, accY[m][nt], 0, 0, 0);
      }
    #pragma unroll
    for (int ks = 0; ks < 2; ++ks) {
      short8 a0f = *reinterpret_cast<const short8*>(&At[0][i0 + lr][ks*32 + kg*8]);
      short8 a1f = *reinterpret_cast<const short8*>(&At[1][i0 + lr][ks*32 + kg*8]);
      short8 b0 = *reinterpret_cast<const short8*>(&VT[lr][ks*32 + kg*8]);
      short8 b1 = *reinterpret_cast<const short8*>(&VT[16 + lr][ks*32 + kg*8]);
      accY[0][0] = __builtin_amdgcn_mfma_f32_16x16x32_bf16(a0f, b0, accY[0][0], 0, 0, 0);
      accY[0][1] = __builtin_amdgcn_mfma_f32_16x16x32_bf16(a0f, b1, accY[0][1], 0, 0, 0);
      accY[1][0] = __builtin_amdgcn_mfma_f32_16x16x32_bf16(a1f, b0, accY[1][0], 0, 0, 0);
      accY[1][1] = __builtin_amdgcn_mfma_f32_16x16x32_bf16(a1f, b1, accY[1][1], 0, 0, 0);
    }
    #pragma unroll
    for (int r = 0; r < 4; ++r) {
      int i = i0 + kg*4 + r;
      float c0 = coef[0][i], c1 = coef[1][i];
      size_t ob = (size_t)(b*TT + t0 + i)*HH + h*32;
      yb[ob + lr]      = f2b(c0*accY[0][0][r] + c1*accY[1][0][r]);
      yb[ob + 16 + lr] = f2b(c0*accY[0][1][r] + c1*accY[1][1][r]);
    }
  }
}

// ---------------- LayerNorm: z = x + zp0 + zp1 + bout, then LN ----------------
__global__ __launch_bounds__(256) void ln_k(
    const float* __restrict__ xr, const float* __restrict__ zp0, const float* __restrict__ zp1,
    const float* __restrict__ bout, const float* __restrict__ g,
    const float* __restrict__ bta, float* __restrict__ out)
{
  const int row = blockIdx.x;
  const int tid = threadIdx.x;
  size_t o = (size_t)row*HH/4 + tid;
  float4 xv = reinterpret_cast<const float4*>(xr)[o];
  float4 z0 = reinterpret_cast<const float4*>(zp0)[o];
  float4 z1 = reinterpret_cast<const float4*>(zp1)[o];
  float4 bo = reinterpret_cast<const float4*>(bout)[tid];
  float4 zv;
  zv.x = xv.x + z0.x + z1.x + bo.x;
  zv.y = xv.y + z0.y + z1.y + bo.y;
  zv.z = xv.z + z0.z + z1.z + bo.z;
  zv.w = xv.w + z0.w + z1.w + bo.w;
  float sum = zv.x+zv.y+zv.z+zv.w;
  float sq  = zv.x*zv.x + zv.y*zv.y + zv.z*zv.z + zv.w*zv.w;
  #pragma unroll
  for (int off=1; off<64; off<<=1){ sum += __shfl_xor(sum, off); sq += __shfl_xor(sq, off); }
  __shared__ float s1[4], s2[4];
  int w = tid>>6;
  if ((tid&63)==0){ s1[w]=sum; s2[w]=sq; }
  __syncthreads();
  sum = s1[0]+s1[1]+s1[2]+s1[3];
  sq  = s2[0]+s2[1]+s2[2]+s2[3];
  float mu  = sum * (1.f/1024.f);
  float var = sq * (1.f/1024.f) - mu*mu;
  float rstd = rsqrtf(var + 1e-5f);
  float4 gv = reinterpret_cast<const float4*>(g)[tid];
  float4 bv = reinterpret_cast<const float4*>(bta)[tid];
  float4 ov;
  ov.x = (zv.x-mu)*rstd*gv.x + bv.x;
  ov.y = (zv.y-mu)*rstd*gv.y + bv.y;
  ov.z = (zv.z-mu)*rstd*gv.z + bv.z;
  ov.w = (zv.w-mu)*rstd*gv.w + bv.w;
  reinterpret_cast<float4*>(out)[o] = ov;
}

extern "C" void kernel_launch(void* const* d_in, const int* in_sizes, int n_in,
                              void* d_out, int out_size, void* d_ws, size_t ws_size,
                              hipStream_t stream)
{
  const float* x     = (const float*)d_in[0];
  const float* Wq    = (const float*)d_in[1];
  const float* Wk    = (const float*)d_in[2];
  const float* Wv    = (const float*)d_in[3];
  const float* Wbeta = (const float*)d_in[4];
  const float* bbeta = (const float*)d_in[5];
  const float* Wmix  = (const float*)d_in[6];
  const float* bmix  = (const float*)d_in[7];
  const float* Wout  = (const float*)d_in[8];
  const float* bout  = (const float*)d_in[9];
  const float* ln_g  = (const float*)d_in[10];
  const float* ln_b  = (const float*)d_in[11];
  float* out = (float*)d_out;

  float* ws = (float*)d_ws;
  float* ct      = ws;                       // 16384
  float* st      = ws + 16384;               // 16384
  u16*   x_bf    = (u16*)(ws + 32768);       // 4194304 u16 (reused as y_bf)
  u16*   Wf      = (u16*)(ws + 2129920);     // 3276800 u16
  u16*   Wout_bf = (u16*)(ws + 3768320);     // 1048576 u16
  u16*   qkv     = (u16*)(ws + 4292608);     // 12582912 u16 (first 4194304 f reused as zp1)
  float* betag   = ws + 10584064;            // 262144
  float* mixg    = ws + 10846208;            // 262144
  float* dSS0    = ws + 11108352;            // 4194304 (reused as zp0)
  float* dKK0    = ws + 15302656;            // 131072
  float* pLg     = ws + 15433728;            // 4096
  float* pg      = ws + 15437824;            // 262144
  u16*   y_bf    = x_bf;
  float* zp0     = dSS0;
  float* zp1     = (float*)qkv;

  cast_all_k<<<8320, 256, 0, stream>>>(x, Wq, Wk, Wv, Wbeta, Wmix, Wout,
                                       x_bf, Wf, Wout_bf, ct, st);
  gemm_qkv_k<<<800, 256, 0, stream>>>(x_bf, Wf, ct, st, bbeta, bmix, qkv, betag, mixg);
  dim3 gscan(NCH, 32, 4);
  scan_delta_k<<<gscan, 256, 0, stream>>>(qkv, betag, dSS0, dKK0, pLg, pg);
  scan_state_k<<<1024, 256, 0, stream>>>(dSS0, dKK0, pLg);
  scan_apply_k<<<gscan, 256, 0, stream>>>(qkv, mixg, dSS0, dKK0, pg, y_bf);
  gemm_out_k<<<512, 256, 0, stream>>>(y_bf, Wout_bf, zp0, zp1);
  ln_k<<<4096, 256, 0, stream>>>(x, zp0, zp1, bout, ln_g, ln_b, out);
}